// Round 17
// baseline (1090.260 us; speedup 1.0000x reference)
//
#include <hip/hip_runtime.h>
#include <math.h>

#define BN_ 8
#define NN 1024
#define KK 20
#define EPSBN 1e-5f
#define FXSCALE 1048576.0f   // 2^20 fixed-point scale for deterministic stats

typedef unsigned long long u64;
typedef unsigned short ushort_t;
typedef __attribute__((ext_vector_type(8))) short short8v;   // 8 bf16 (4 VGPRs)
typedef __attribute__((ext_vector_type(4))) float f32x4;     // MFMA acc

__device__ __forceinline__ float lrelu(float x){ return x > 0.f ? x : 0.2f*x; }

__device__ __forceinline__ unsigned fmap(float x){
  unsigned u = __float_as_uint(x);
  return (u & 0x80000000u) ? ~u : (u | 0x80000000u);
}
__device__ __forceinline__ float funmap(unsigned m){
  unsigned u = (m & 0x80000000u) ? (m & 0x7FFFFFFFu) : ~m;
  return __uint_as_float(u);
}
__device__ __forceinline__ ushort_t f2b(float f){   // RNE fp32 -> bf16 bits
  unsigned u = __float_as_uint(f);
  unsigned r = (u + 0x7FFFu + ((u >> 16) & 1u)) >> 16;
  return (ushort_t)r;
}

__device__ __forceinline__ int mbcnt64(u64 m){
  return __builtin_amdgcn_mbcnt_hi((unsigned)(m >> 32),
         __builtin_amdgcn_mbcnt_lo((unsigned)m, 0));
}

__device__ __forceinline__ void statadd(u64* SP, int O, int ch, int o, float s, float s2){
  atomicAdd(&SP[(size_t)ch*2*O + o],     (u64)(long long)llrintf(s  * FXSCALE));
  atomicAdd(&SP[(size_t)ch*2*O + O + o], (u64)(long long)llrintf(s2 * FXSCALE));
}

// ---------- transpose [B,C,N]->[B,N,C] + per-point sum of squares (C=3 paths) ----------
__global__ void k_transq(const float* __restrict__ src, long bs, int C,
                         float* __restrict__ xt, float* __restrict__ xx)
{
  int g = blockIdx.x*256 + threadIdx.x;
  if (g >= BN_*NN) return;
  int b = g >> 10, n = g & 1023;
  const float* s = src + (long)b*bs + n;
  float* d = xt + (long)g*C;
  float ss = 0.f;
  for (int c = 0; c < C; ++c){ float v = s[(long)c*NN]; d[c] = v; ss += v*v; }
  xx[g] = ss;
}

// ---------- fused pairwise-dist (float4 loads) + top-20 radix-select ----------
__global__ __launch_bounds__(256) void k_knn(
    const float* __restrict__ X, long bsX,
    const float* __restrict__ XT, const float* __restrict__ XX,
    int* __restrict__ IDX, int C)
{
  extern __shared__ float sm[];          // xi for block's 8 rows: [8*C]
  int tid = threadIdx.x;
  int wave = tid >> 6, lane = tid & 63;
  int b = blockIdx.x >> 7;
  int i0 = (blockIdx.x & 127) << 3;
  for (int t = tid; t < 8*C; t += 256){
    int rr = t / C, cc = t - rr*C;
    sm[t] = XT[((long)(b<<10) + i0 + rr)*C + cc];
  }
  __syncthreads();
  const float* xb = X + (long)b*bsX;
  float acc[2][16];
  #pragma unroll
  for (int r=0;r<2;r++)
    #pragma unroll
    for (int q=0;q<16;q++) acc[r][q]=0.f;
  const float* xi = sm + (wave*2)*C;
  for (int c = 0; c < C; ++c){
    const float4* xr4 = (const float4*)(xb + (long)c*NN);
    float4 xv4[4];
    #pragma unroll
    for (int q4=0;q4<4;q4++) xv4[q4] = xr4[q4*64 + lane];
    #pragma unroll
    for (int r=0;r<2;r++){
      float xiv = xi[r*C + c];
      #pragma unroll
      for (int q4=0;q4<4;q4++){
        acc[r][q4*4+0] = fmaf(xiv, xv4[q4].x, acc[r][q4*4+0]);
        acc[r][q4*4+1] = fmaf(xiv, xv4[q4].y, acc[r][q4*4+1]);
        acc[r][q4*4+2] = fmaf(xiv, xv4[q4].z, acc[r][q4*4+2]);
        acc[r][q4*4+3] = fmaf(xiv, xv4[q4].w, acc[r][q4*4+3]);
      }
    }
  }
  const float4* xx4 = (const float4*)(XX + (b<<10));
  float xxj[16];
  #pragma unroll
  for (int q4=0;q4<4;q4++){
    float4 t = xx4[q4*64 + lane];
    xxj[q4*4+0]=t.x; xxj[q4*4+1]=t.y; xxj[q4*4+2]=t.z; xxj[q4*4+3]=t.w;
  }
  const float* xxb = XX + (b<<10);
  int row0 = i0 + wave*2;
  #pragma unroll
  for (int r=0;r<2;r++){
    float xxi = xxb[row0 + r];
    #pragma unroll
    for (int q=0;q<16;q++) acc[r][q] = 2.f*acc[r][q] - xxi - xxj[q];
  }

  for (int r=0;r<2;r++){
    unsigned u[16];
    #pragma unroll
    for (int q=0;q<16;q++) u[q] = fmap(acc[r][q]);
    unsigned P = 0;
    for (int bit = 31; bit >= 0; --bit){
      unsigned cand = P | (1u << bit);
      int c = 0;
      #pragma unroll
      for (int q=0;q<16;q++) c += (int)__popcll(__ballot(u[q] >= cand));
      if (c >= KK) P = cand;
    }
    int nG = 0;
    #pragma unroll
    for (int q=0;q<16;q++) nG += (int)__popcll(__ballot(u[q] > P));
    int navail = KK - nG;
    int slot = 0;
    int outb = ((b<<10) + row0 + r)*KK;
    #pragma unroll
    for (int q=0;q<16;q++){
      u64 mg = __ballot(u[q] > P);
      u64 me = __ballot(u[q] == P);
      int cg = (int)__popcll(mg);
      int ce = (int)__popcll(me);
      int take_e = navail < ce ? navail : ce;
      int nval = ((q >> 2) << 8) + (lane << 2) + (q & 3);
      if (u[q] > P){
        IDX[outb + slot + mbcnt64(mg)] = nval;
      } else if (u[q] == P){
        int rk = mbcnt64(me);
        if (rk < take_e) IDX[outb + slot + cg + rk] = nval;
      }
      slot += cg + take_e;
      navail -= take_e;
    }
  }
}

// ---------- old-style edge-conv for C=3 layers: writes coalesced YMT[bn][o] ----------
__global__ void k_edgeconv3(const float* __restrict__ XT, const int* __restrict__ IDX,
                            const float* __restrict__ W, float* __restrict__ YMT,
                            u64* __restrict__ SP)
{
  __shared__ float nb[KK*3];
  __shared__ float ctr[3];
  __shared__ int is[KK];
  const int C = 3, O = 64;
  int tid = threadIdx.x;
  int bn = blockIdx.x;
  int b = bn >> 10;
  if (tid < KK) is[tid] = IDX[bn*KK + tid];
  __syncthreads();
  if (tid < 60){ int k = tid/3, c = tid - k*3; nb[tid] = XT[((long)(b<<10)+is[k])*C + c]; }
  if (tid < 3) ctr[tid] = XT[(long)bn*C + tid];
  __syncthreads();
  int o = tid;
  const float* wp = W + (long)o*2*C;
  float yc = 0.f;
  #pragma unroll
  for (int c = 0; c < 3; ++c) yc = fmaf(wp[C+c] - wp[c], ctr[c], yc);
  float acc[KK];
  #pragma unroll
  for (int k=0;k<KK;k++) acc[k] = yc;
  #pragma unroll
  for (int c = 0; c < 3; ++c){
    float wf = wp[c];
    #pragma unroll
    for (int k=0;k<KK;k++) acc[k] = fmaf(wf, nb[k*3+c], acc[k]);
  }
  float mx = -INFINITY, s = 0.f, s2 = 0.f;
  #pragma unroll
  for (int k=0;k<KK;k++){ float v = acc[k]; mx = fmaxf(mx, v); s += v; s2 = fmaf(v,v,s2); }
  YMT[(long)bn*O + o] = mx;
  statadd(SP, O, bn & 63, o, s, s2);
}

// ---------- dense per-point GEMM: AB[bn][2O] = [Wf@x ; (Wc-Wf)@x] ----------
template<int C, int O>
__global__ __launch_bounds__(256, 4) void k_gemm_ab(
    const float* __restrict__ XT, const float* __restrict__ WP,
    float* __restrict__ AB)
{
  constexpr int P = 16;
  constexpr int TWO = 2*O;
  constexpr int CO = (TWO + 255)/256;
  __shared__ __align__(16) float Xs[P][C];
  int tid = threadIdx.x;
  long bn0 = (long)blockIdx.x * P;
  for (int t = tid; t < P*C; t += 256) (&Xs[0][0])[t] = XT[bn0*C + t];
  __syncthreads();
  float acc[CO][P];
  #pragma unroll
  for (int j=0;j<CO;j++)
    #pragma unroll
    for (int r=0;r<P;r++) acc[j][r] = 0.f;
  for (int c4 = 0; c4 < C/4; ++c4){
    float4 w[CO];
    #pragma unroll
    for (int j=0;j<CO;j++){
      int o = tid + j*256;
      if (o < TWO) w[j] = *(const float4*)(WP + ((size_t)c4*TWO + o)*4);
    }
    #pragma unroll
    for (int r=0;r<P;r++){
      float4 xv = *(const float4*)(&Xs[r][c4*4]);
      #pragma unroll
      for (int j=0;j<CO;j++){
        acc[j][r] = fmaf(w[j].x, xv.x, acc[j][r]);
        acc[j][r] = fmaf(w[j].y, xv.y, acc[j][r]);
        acc[j][r] = fmaf(w[j].z, xv.z, acc[j][r]);
        acc[j][r] = fmaf(w[j].w, xv.w, acc[j][r]);
      }
    }
  }
  #pragma unroll
  for (int j=0;j<CO;j++){
    int o = tid + j*256;
    if (o < TWO)
      for (int r=0;r<P;r++) AB[(bn0 + r)*TWO + o] = acc[j][r];
  }
}

// ---------- gather-reduce: y = A[idx] + B[n]; max/sum/sumsq over k ----------
template<int O, int P>
__global__ __launch_bounds__(256) void k_egather(
    const float* __restrict__ AB, const int* __restrict__ IDX,
    float* __restrict__ YMT, u64* __restrict__ SP)
{
  constexpr int TWO = 2*O;
  constexpr int S = 256/O;
  constexpr int PS = P/S;
  __shared__ int is[P][KK];
  int tid = threadIdx.x;
  long bn0 = (long)blockIdx.x * P;
  long b10 = (bn0 >> 10) << 10;
  for (int t = tid; t < P*KK; t += 256) (&is[0][0])[t] = IDX[bn0*KK + t];
  __syncthreads();
  int strand = tid / O;
  int o = tid - strand*O;
  float s = 0.f, s2 = 0.f;
  #pragma unroll
  for (int ps = 0; ps < PS; ++ps){
    int p = strand*PS + ps;
    long bn = bn0 + p;
    float bv = AB[bn*TWO + O + o];
    float mx = -INFINITY;
    #pragma unroll
    for (int k = 0; k < KK; ++k){
      long row = b10 + is[p][k];
      float v = AB[row*TWO + o] + bv;
      mx = fmaxf(mx, v);
      s += v; s2 = fmaf(v,v,s2);
    }
    YMT[bn*O + o] = mx;
  }
  int ch = ((int)blockIdx.x * S + strand) & 63;
  statadd(SP, O, ch, o, s, s2);
}

// ---------- stats finalize: mean + invstd (fixed-order integer sum: exact) ----------
__global__ void k_bnfin(const u64* __restrict__ SP, float* __restrict__ MV, int O, float cnt)
{
  int o = blockIdx.x*blockDim.x + threadIdx.x;
  if (o >= O) return;
  long long S = 0, S2 = 0;
  for (int ch = 0; ch < 64; ++ch){
    S  += (long long)SP[(size_t)ch*2*O + o];
    S2 += (long long)SP[(size_t)ch*2*O + O + o];
  }
  double m = (double)S / ((double)FXSCALE * (double)cnt);
  double ms2 = (double)S2 / ((double)FXSCALE * (double)cnt);
  double var = ms2 - m*m;
  MV[o] = (float)m;
  MV[O + o] = (float)(1.0 / sqrt(var + (double)EPSBN));
}

// ---------- t-net conv2 (recompute conv1 in LDS), RO=2, b128 h1 reads ----------
__global__ __launch_bounds__(64) void k_tconv2(
    const float* __restrict__ XT, const int* __restrict__ IDX,
    const float* __restrict__ W1, const float* __restrict__ MV1,
    const float* __restrict__ W2T, float* __restrict__ M2T, u64* __restrict__ SP)
{
  __shared__ float nb[KK*3];
  __shared__ float ctr[3];
  __shared__ __align__(16) float h1t[64*KK];   // [o][k]
  __shared__ int is[KK];
  int tid = threadIdx.x;               // 64
  int bn = blockIdx.x;
  int b = bn >> 10;
  if (tid < KK) is[tid] = IDX[bn*KK + tid];
  __syncthreads();
  if (tid < 60){ int k = tid/3, c = tid - k*3; nb[tid] = XT[((long)(b<<10)+is[k])*3 + c]; }
  if (tid < 3) ctr[tid] = XT[(long)bn*3 + tid];
  __syncthreads();
  {
    const float* wp = W1 + tid*6;
    float w0=wp[0], w1=wp[1], w2=wp[2];
    float cterm = fmaf(wp[3]-w0, ctr[0], fmaf(wp[4]-w1, ctr[1], (wp[5]-w2)*ctr[2]));
    float m = MV1[tid], iv = MV1[64+tid];
    #pragma unroll
    for (int k=0;k<KK;k++){
      float y = cterm;
      y = fmaf(w0, nb[k*3],   y);
      y = fmaf(w1, nb[k*3+1], y);
      y = fmaf(w2, nb[k*3+2], y);
      h1t[tid*KK + k] = lrelu((y - m) * iv);
    }
  }
  __syncthreads();
  float acc[2][KK];
  #pragma unroll
  for (int j=0;j<2;j++)
    #pragma unroll
    for (int k=0;k<KK;k++) acc[j][k]=0.f;
  #pragma unroll 2
  for (int c=0;c<64;++c){
    float wv0 = W2T[c*128 + tid];
    float wv1 = W2T[c*128 + 64 + tid];
    const float4* hp = (const float4*)(h1t + c*KK);
    float hv[KK];
    #pragma unroll
    for (int q=0;q<5;q++){
      float4 v4 = hp[q];
      hv[q*4]=v4.x; hv[q*4+1]=v4.y; hv[q*4+2]=v4.z; hv[q*4+3]=v4.w;
    }
    #pragma unroll
    for (int k=0;k<KK;k++){
      acc[0][k] = fmaf(wv0, hv[k], acc[0][k]);
      acc[1][k] = fmaf(wv1, hv[k], acc[1][k]);
    }
  }
  int ch = bn & 63;
  #pragma unroll
  for (int j=0;j<2;j++){
    int o = tid + j*64;
    float mx=-INFINITY, s=0.f, s2=0.f;
    #pragma unroll
    for (int k=0;k<KK;k++){ float v = acc[j][k]; mx = fmaxf(mx, v); s += v; s2 = fmaf(v,v,s2); }
    M2T[(long)bn*128 + o] = mx;
    statadd(SP, 128, ch, o, s, s2);
  }
}

// ---------- BN+lrelu from [bn][O] -> [b][*][n] dst (+ optional XT/xx + bf16 XB row) ----------
__global__ __launch_bounds__(256) void k_apply_t(
    const float* __restrict__ SRC, const float* __restrict__ MV,
    int O, float* __restrict__ DST, long dbs, int choff,
    float* __restrict__ XTN, float* __restrict__ XXN,
    ushort_t* __restrict__ XB)
{
  int bn = blockIdx.x*256 + threadIdx.x;
  if (bn >= BN_*NN) return;
  int b = bn >> 10, n = bn & 1023;
  const float4* src = (const float4*)(SRC + (long)bn*O);
  float4* xo = XTN ? (float4*)(XTN + (long)bn*O) : nullptr;
  u64* xbw = XB ? (u64*)(XB + (size_t)bn*512 + choff) : nullptr;
  float ss = 0.f;
  for (int o4 = 0; o4 < O/4; ++o4){
    float4 v = src[o4];
    float vv[4] = {v.x, v.y, v.z, v.w};
    float rr[4];
    #pragma unroll
    for (int u=0;u<4;u++){
      int o = o4*4+u;
      float t = lrelu((vv[u] - MV[o]) * MV[O+o]);
      rr[u] = t;
      ss = fmaf(t,t,ss);
      DST[(long)b*dbs + (long)(choff+o)*NN + n] = t;
    }
    if (xo) xo[o4] = make_float4(rr[0],rr[1],rr[2],rr[3]);
    if (xbw){
      u64 pk = (u64)f2b(rr[0]) | ((u64)f2b(rr[1]) << 16)
             | ((u64)f2b(rr[2]) << 32) | ((u64)f2b(rr[3]) << 48);
      xbw[o4] = pk;
    }
  }
  if (XXN) XXN[bn] = ss;
}

// ---------- weight transpose [O][C] -> [C][O] ----------
__global__ void k_wprep_t(const float* __restrict__ W, float* __restrict__ WT, int O, int C)
{
  int g = blockIdx.x*256+threadIdx.x;
  if (g >= O*C) return;
  int o = g / C, c = g - o*C;
  WT[(long)c*O + o] = W[g];
}

// ---------- quad weight pack for k_gemm_sm: [1024][C] -> WQ[c][t][4] ----------
__global__ void k_wprep_q(const float* __restrict__ W, float* __restrict__ WQ, int C)
{
  int g = blockIdx.x*256+threadIdx.x;
  if (g >= 1024*C) return;
  int o = g / C, c = g - o*C;
  int j = o >> 8, t = o & 255;
  WQ[((size_t)c*256 + t)*4 + j] = W[g];
}

// ---------- MFMA B-operand pack: w6[1024][512] -> bf16 frags ----------
__global__ void k_wprep_mf(const float* __restrict__ W, ushort_t* __restrict__ WB)
{
  int g = blockIdx.x*256+threadIdx.x;
  if (g >= 1024*512) return;
  int o = g >> 9, c = g & 511;
  int ks = c >> 5, kk = c & 31;
  int l = (kk >> 3)*16 + (o & 15);
  int e = kk & 7;
  WB[(((size_t)(o >> 4)*16 + ks)*64 + l)*8 + e] = f2b(W[g]);
}

// ---------- edge weight prep: [O][2C] -> packed WP [C/4][2O][4] ----------
__global__ void k_wprep_e2(const float* __restrict__ W, float* __restrict__ WP, int O, int C)
{
  int g = blockIdx.x*256+threadIdx.x;
  if (g >= O*C) return;
  int o = g / C, c = g - o*C;
  float wf = W[(long)o*2*C + c];
  float wc = W[(long)o*2*C + C + c];
  size_t base = ((size_t)(c>>2)*(2*O))*4 + (c&3);
  WP[base + (size_t)o*4]       = wf;
  WP[base + (size_t)(O+o)*4]   = wc - wf;
}

// ---------- dense GEMM (R13 proven): RO=4, n-tile 16, scalar X, W depth-2 prefetch ----------
__global__ __launch_bounds__(256, 1) void k_gemm_sm(
    const float* __restrict__ WQ, const float* __restrict__ X,
    long bsX, int C, unsigned* __restrict__ MX, u64* __restrict__ SP)
{
  int tid = threadIdx.x;
  int bt = blockIdx.x;
  int b = bt >> 6;
  int n0 = (bt & 63) << 4;
  const float* xrow = X + (long)b*bsX + n0;
  float acc[4][16];
  #pragma unroll
  for (int j=0;j<4;j++)
    #pragma unroll
    for (int i=0;i<16;i++) acc[j][i]=0.f;
  const float4* wq = (const float4*)WQ;

  auto gemm_step = [&](int cc, float4 wv){
    const float4* xc = (const float4*)(xrow + (size_t)cc*NN);
    float4 xa = xc[0], xb2 = xc[1], xe = xc[2], xf = xc[3];
    float wj[4] = {wv.x, wv.y, wv.z, wv.w};
    #pragma unroll
    for (int j=0;j<4;j++){
      float ww = wj[j];
      acc[j][0]=fmaf(ww,xa.x,acc[j][0]);  acc[j][1]=fmaf(ww,xa.y,acc[j][1]);
      acc[j][2]=fmaf(ww,xa.z,acc[j][2]);  acc[j][3]=fmaf(ww,xa.w,acc[j][3]);
      acc[j][4]=fmaf(ww,xb2.x,acc[j][4]);  acc[j][5]=fmaf(ww,xb2.y,acc[j][5]);
      acc[j][6]=fmaf(ww,xb2.z,acc[j][6]);  acc[j][7]=fmaf(ww,xb2.w,acc[j][7]);
      acc[j][8]=fmaf(ww,xe.x,acc[j][8]);  acc[j][9]=fmaf(ww,xe.y,acc[j][9]);
      acc[j][10]=fmaf(ww,xe.z,acc[j][10]); acc[j][11]=fmaf(ww,xe.w,acc[j][11]);
      acc[j][12]=fmaf(ww,xf.x,acc[j][12]); acc[j][13]=fmaf(ww,xf.y,acc[j][13]);
      acc[j][14]=fmaf(ww,xf.z,acc[j][14]); acc[j][15]=fmaf(ww,xf.w,acc[j][15]);
    }
  };

  float4 w0 = wq[tid];
  float4 w1 = wq[256 + tid];
  for (int c = 0; c < C-2; c += 2){
    float4 p0 = wq[(size_t)(c+2)*256 + tid];
    float4 p1 = wq[(size_t)(c+3)*256 + tid];
    gemm_step(c,   w0);
    gemm_step(c+1, w1);
    w0 = p0; w1 = p1;
  }
  gemm_step(C-2, w0);
  gemm_step(C-1, w1);

  int ch = bt & 63;
  #pragma unroll
  for (int j=0;j<4;j++){
    int o = tid + j*256;
    float mx=-INFINITY, s=0.f, s2=0.f;
    #pragma unroll
    for (int i=0;i<16;i++){ float v=acc[j][i]; mx=fmaxf(mx,v); s+=v; s2=fmaf(v,v,s2); }
    atomicMax(&MX[(b<<10) + o], fmap(mx));
    statadd(SP, 1024, ch, o, s, s2);
  }
}

// ---------- MFMA bf16 GEMM for w6: y^T[n][o] tiles, fused max/stats ----------
__global__ __launch_bounds__(256) void k_gemm_mfma(
    const ushort_t* __restrict__ WB, const ushort_t* __restrict__ XB,
    unsigned* __restrict__ MX, u64* __restrict__ SP)
{
  int tid = threadIdx.x;
  int w = tid >> 6, lane = tid & 63;
  int b = blockIdx.x >> 4;
  int ob = blockIdx.x & 15;
  int otile = ob*4 + w;              // 0..63
  int o0 = otile << 4;
  short8v wfrag[16];
  const short8v* wp = (const short8v*)WB;
  #pragma unroll
  for (int ks=0; ks<16; ++ks)
    wfrag[ks] = wp[((size_t)otile*16 + ks)*64 + lane];

  float mx = -INFINITY, s = 0.f, s2 = 0.f;
  int nbase = blockIdx.y*256;
  for (int nt = 0; nt < 16; ++nt){
    int n0 = nbase + nt*16;
    const short8v* xp = (const short8v*)(XB + ((size_t)(b<<10) + n0 + (lane & 15))*512 + (lane >> 4)*8);
    f32x4 acc = {0.f, 0.f, 0.f, 0.f};
    #pragma unroll
    for (int ks=0; ks<16; ++ks){
      short8v a = xp[ks*4];
      acc = __builtin_amdgcn_mfma_f32_16x16x32_bf16(a, wfrag[ks], acc, 0, 0, 0);
    }
    #pragma unroll
    for (int reg=0; reg<4; ++reg){
      float v = acc[reg];
      mx = fmaxf(mx, v); s += v; s2 = fmaf(v, v, s2);
    }
  }
  #pragma unroll
  for (int off=16; off<=32; off<<=1){
    mx = fmaxf(mx, __shfl_xor(mx, off));
    s += __shfl_xor(s, off);
    s2 += __shfl_xor(s2, off);
  }
  if (lane < 16){
    int o = o0 + lane;
    atomicMax(&MX[(b<<10) + o], fmap(mx));
    int ch = ((blockIdx.x << 2) + w + (blockIdx.y << 4)) & 63;
    statadd(SP, 1024, ch, o, s, s2);
  }
}

// ---------- unmap max + BN + lrelu ----------
__global__ void k_finmax(const unsigned* __restrict__ MX, const float* __restrict__ MV,
                         float* __restrict__ OUT)
{
  int g = blockIdx.x*256+threadIdx.x;
  if (g >= BN_*1024) return;
  int o = g & 1023;
  OUT[g] = lrelu((funmap(MX[g]) - MV[o]) * MV[1024+o]);
}

// ---------- fused FC + batch-BN + lrelu: one wave per feature ----------
__global__ __launch_bounds__(256) void k_fcbn(
    const float* __restrict__ A, const float* __restrict__ W,
    const float* __restrict__ bias, int C, int F, float* __restrict__ Z)
{
  int wv = threadIdx.x >> 6, lane = threadIdx.x & 63;
  int f = blockIdx.x*4 + wv;
  if (f >= F) return;
  const float* w = W + (long)f*C;
  float acc[8];
  #pragma unroll
  for (int b=0;b<8;b++) acc[b]=0.f;
  for (int c = lane; c < C; c += 64){
    float wvv = w[c];
    #pragma unroll
    for (int b=0;b<8;b++) acc[b] = fmaf(wvv, A[b*C + c], acc[b]);
  }
  #pragma unroll
  for (int b=0;b<8;b++){
    #pragma unroll
    for (int off=32; off>0; off>>=1) acc[b] += __shfl_xor(acc[b], off);
  }
  float bs = bias ? bias[f] : 0.f;
  float m = 0.f;
  #pragma unroll
  for (int b=0;b<8;b++){ acc[b] += bs; m += acc[b]; }
  m *= 0.125f;
  float var = 0.f;
  #pragma unroll
  for (int b=0;b<8;b++){ float d = acc[b]-m; var = fmaf(d,d,var); }
  var *= 0.125f;
  float is = rsqrtf(var + EPSBN);
  if (lane < 8) Z[lane*F + f] = lrelu((acc[lane]-m)*is);
}

// ---------- fc3 + bias + eye -> T[8,9], one wave per output ----------
__global__ __launch_bounds__(256) void k_fc3w(
    const float* __restrict__ A, const float* __restrict__ W,
    const float* __restrict__ bias, float* __restrict__ T9)
{
  int g = blockIdx.x*4 + (threadIdx.x >> 6);
  int lane = threadIdx.x & 63;
  if (g >= 72) return;
  int b = g / 9, j = g - b*9;
  const float* a = A + b*256;
  const float* w = W + j*256;
  float s = 0.f;
  for (int c = lane; c < 256; c += 64) s = fmaf(a[c], w[c], s);
  #pragma unroll
  for (int off=32; off>0; off>>=1) s += __shfl_xor(s, off);
  if (lane == 0){
    s += bias[j];
    if (j==0 || j==4 || j==8) s += 1.f;
    T9[g] = s;
  }
}

// ---------- apply 3x3 transform: xtr = T @ x ----------
__global__ void k_tapply(const float* __restrict__ Xin, const float* __restrict__ T9,
                         float* __restrict__ Xtr)
{
  int g = blockIdx.x*256+threadIdx.x;
  if (g >= BN_*3*NN) return;
  int n = g & 1023;
  int i = (g >> 10) % 3;
  int b = g / (3*NN);
  const float* t = T9 + b*9 + i*3;
  const float* xb = Xin + (long)b*3*NN + n;
  Xtr[g] = fmaf(t[0], xb[0], fmaf(t[1], xb[NN], t[2]*xb[2*NN]));
}

extern "C" void kernel_launch(void* const* d_in, const int* in_sizes, int n_in,
                              void* d_out, int out_size, void* d_ws, size_t ws_size,
                              hipStream_t stream)
{
  (void)in_sizes; (void)n_in; (void)out_size;
  const float* x     = (const float*)d_in[0];
  const float* tw1   = (const float*)d_in[1];
  const float* tw2   = (const float*)d_in[2];
  const float* tw3   = (const float*)d_in[3];
  const float* tfc1w = (const float*)d_in[4];
  const float* tfc2w = (const float*)d_in[5];
  const float* tfc2b = (const float*)d_in[6];
  const float* tfc3w = (const float*)d_in[7];
  const float* tfc3b = (const float*)d_in[8];
  const float* w1    = (const float*)d_in[9];
  const float* w2    = (const float*)d_in[10];
  const float* w3    = (const float*)d_in[11];
  const float* w4    = (const float*)d_in[12];
  const float* w6    = (const float*)d_in[13];
  float* out = (float*)d_out;

  char* ws = (char*)d_ws;
  size_t off = 0;
  auto alloc = [&](size_t bytes) -> void* {
    off = (off + 255) & ~(size_t)255;
    void* p = ws + off;
    off += bytes;
    return p;
  };
  auto spb = [](int O){ return (size_t)64*2*O*8; };

  float*    xt   = (float*)alloc((size_t)BN_*NN*128*4);
  float*    xx   = (float*)alloc((size_t)BN_*NN*4);
  int*      idx  = (int*)  alloc((size_t)BN_*NN*KK*4);
  float*    ymt  = (float*)alloc((size_t)BN_*NN*256*4);   // also m2t
  float*    ab   = (float*)alloc((size_t)BN_*NN*512*4);
  float*    xcat = (float*)alloc((size_t)BN_*512*NN*4);
  float*    xtr  = (float*)alloc((size_t)BN_*3*NN*4);
  float*    m2   = (float*)alloc((size_t)BN_*128*NN*4);
  ushort_t* xb16 = (ushort_t*)alloc((size_t)BN_*NN*512*2);
  ushort_t* wb16 = (ushort_t*)alloc((size_t)1024*512*2);
  // --- zero-once region ---
  size_t zoff0 = (off + 255) & ~(size_t)255;
  u64*      sp_e1 = (u64*)alloc(spb(64));
  u64*      sp_tc = (u64*)alloc(spb(128));
  u64*      sp_g1 = (u64*)alloc(spb(1024));
  u64*      sp_L1 = (u64*)alloc(spb(64));
  u64*      sp_L2 = (u64*)alloc(spb(64));
  u64*      sp_L3 = (u64*)alloc(spb(128));
  u64*      sp_L4 = (u64*)alloc(spb(256));
  u64*      sp_g2 = (u64*)alloc(spb(1024));
  unsigned* mxu1  = (unsigned*)alloc((size_t)BN_*1024*4);
  unsigned* mxu2  = (unsigned*)alloc((size_t)BN_*1024*4);
  size_t ztotal = off - zoff0;
  // --- end zero-once region ---
  float*    mv1  = (float*)alloc(2*64*4);
  float*    mv2  = (float*)alloc(2*128*4);
  float*    mv3  = (float*)alloc(2*1024*4);
  float*    mvL  = (float*)alloc(2*256*4);
  float*    mv6  = (float*)alloc(2*1024*4);
  float*    vbuf = (float*)alloc((size_t)BN_*1024*4);
  float*    z1   = (float*)alloc((size_t)BN_*512*4);
  float*    z2   = (float*)alloc((size_t)BN_*256*4);
  float*    T9   = (float*)alloc(72*4);
  float*    wt3q = (float*)alloc((size_t)128*1024*4);
  float*    wt2t = (float*)alloc((size_t)64*128*4);
  float*    w2p  = (float*)alloc((size_t)64*128*4);
  float*    w3p  = (float*)alloc((size_t)64*256*4);
  float*    w4p  = (float*)alloc((size_t)128*512*4);
  if (off > ws_size) return;

  float* m2t = ymt;

  const float CNTK = 8.f*1024.f*20.f;
  const float CNTN = 8.f*1024.f;

  hipMemsetAsync((char*)ws + zoff0, 0, ztotal, stream);

  // ===== weight prep =====
  k_wprep_t<<<(128*64+255)/256, 256, 0, stream>>>(tw2, wt2t, 128, 64);
  k_wprep_q<<<(1024*128)/256, 256, 0, stream>>>(tw3, wt3q, 128);
  k_wprep_mf<<<(1024*512)/256, 256, 0, stream>>>(w6, wb16);
  k_wprep_e2<<<(64*64+255)/256, 256, 0, stream>>>(w2, w2p, 64, 64);
  k_wprep_e2<<<(128*64+255)/256, 256, 0, stream>>>(w3, w3p, 128, 64);
  k_wprep_e2<<<(256*128+255)/256, 256, 0, stream>>>(w4, w4p, 256, 128);

  // ===== transform net =====
  k_transq<<<32, 256, 0, stream>>>(x, 3L*NN, 3, xt, xx);
  k_knn<<<1024, 256, 8*3*4, stream>>>(x, 3L*NN, xt, xx, idx, 3);
  k_edgeconv3<<<BN_*NN, 64, 0, stream>>>(xt, idx, tw1, ymt, sp_e1);
  k_bnfin<<<1, 64, 0, stream>>>(sp_e1, mv1, 64, CNTK);
  k_tconv2<<<BN_*NN, 64, 0, stream>>>(xt, idx, tw1, mv1, wt2t, m2t, sp_tc);
  k_bnfin<<<2, 64, 0, stream>>>(sp_tc, mv2, 128, CNTK);
  k_apply_t<<<32, 256, 0, stream>>>(m2t, mv2, 128, m2, 128L*NN, 0, nullptr, nullptr, nullptr);
  k_gemm_sm<<<BN_*64, 256, 0, stream>>>(wt3q, m2, 128L*NN, 128, mxu1, sp_g1);
  k_bnfin<<<16, 64, 0, stream>>>(sp_g1, mv3, 1024, CNTN);
  k_finmax<<<32, 256, 0, stream>>>(mxu1, mv3, vbuf);
  k_fcbn<<<128, 256, 0, stream>>>(vbuf, tfc1w, nullptr, 1024, 512, z1);
  k_fcbn<<<64, 256, 0, stream>>>(z1, tfc2w, tfc2b, 512, 256, z2);
  k_fc3w<<<18, 256, 0, stream>>>(z2, tfc3w, tfc3b, T9);
  k_tapply<<<(BN_*3*NN)/256, 256, 0, stream>>>(x, T9, xtr);

  // ===== edge conv stack =====
  k_transq<<<32, 256, 0, stream>>>(xtr, 3L*NN, 3, xt, xx);
  k_knn<<<1024, 256, 8*3*4, stream>>>(xtr, 3L*NN, xt, xx, idx, 3);
  k_edgeconv3<<<BN_*NN, 64, 0, stream>>>(xt, idx, w1, ymt, sp_L1);
  k_bnfin<<<1, 64, 0, stream>>>(sp_L1, mvL, 64, CNTK);
  k_apply_t<<<32, 256, 0, stream>>>(ymt, mvL, 64, xcat, 512L*NN, 0, xt, xx, xb16);
  // L2
  k_knn<<<1024, 256, 8*64*4, stream>>>(xcat, 512L*NN, xt, xx, idx, 64);
  k_gemm_ab<64,64><<<512, 256, 0, stream>>>(xt, w2p, ab);
  k_egather<64,16><<<512, 256, 0, stream>>>(ab, idx, ymt, sp_L2);
  k_bnfin<<<1, 64, 0, stream>>>(sp_L2, mvL, 64, CNTK);
  k_apply_t<<<32, 256, 0, stream>>>(ymt, mvL, 64, xcat, 512L*NN, 64, xt, xx, xb16);
  // L3
  k_knn<<<1024, 256, 8*64*4, stream>>>(xcat + 64L*NN, 512L*NN, xt, xx, idx, 64);
  k_gemm_ab<64,128><<<512, 256, 0, stream>>>(xt, w3p, ab);
  k_egather<128,16><<<512, 256, 0, stream>>>(ab, idx, ymt, sp_L3);
  k_bnfin<<<2, 64, 0, stream>>>(sp_L3, mvL, 128, CNTK);
  k_apply_t<<<32, 256, 0, stream>>>(ymt, mvL, 128, xcat, 512L*NN, 128, xt, xx, xb16);
  // L4
  k_knn<<<1024, 256, 8*128*4, stream>>>(xcat + 128L*NN, 512L*NN, xt, xx, idx, 128);
  k_gemm_ab<128,256><<<512, 256, 0, stream>>>(xt, w4p, ab);
  k_egather<256,16><<<512, 256, 0, stream>>>(ab, idx, ymt, sp_L4);
  k_bnfin<<<4, 64, 0, stream>>>(sp_L4, mvL, 256, CNTK);
  k_apply_t<<<32, 256, 0, stream>>>(ymt, mvL, 256, xcat, 512L*NN, 256, nullptr, nullptr, xb16);

  // ===== final conv w6 via MFMA bf16 + BN + lrelu + max over N =====
  k_gemm_mfma<<<dim3(BN_*16, 4), 256, 0, stream>>>(wb16, xb16, mxu2, sp_g2);
  k_bnfin<<<16, 64, 0, stream>>>(sp_g2, mv6, 1024, CNTN);
  k_finmax<<<32, 256, 0, stream>>>(mxu2, mv6, out);
}

// Round 18
// 831.059 us; speedup vs baseline: 1.3119x; 1.3119x over previous
//
#include <hip/hip_runtime.h>
#include <math.h>

#define BN_ 8
#define NN 1024
#define KK 20
#define EPSBN 1e-5f
#define FXSCALE 1048576.0f   // 2^20 fixed-point scale for deterministic stats

typedef unsigned long long u64;
typedef unsigned short ushort_t;
typedef __attribute__((ext_vector_type(8))) short short8v;   // 8 bf16 (4 VGPRs)
typedef __attribute__((ext_vector_type(4))) float f32x4;     // MFMA acc

__device__ __forceinline__ float lrelu(float x){ return x > 0.f ? x : 0.2f*x; }

__device__ __forceinline__ unsigned fmap(float x){
  unsigned u = __float_as_uint(x);
  return (u & 0x80000000u) ? ~u : (u | 0x80000000u);
}
__device__ __forceinline__ float funmap(unsigned m){
  unsigned u = (m & 0x80000000u) ? (m & 0x7FFFFFFFu) : ~m;
  return __uint_as_float(u);
}
__device__ __forceinline__ ushort_t f2b(float f){   // RNE fp32 -> bf16 bits
  unsigned u = __float_as_uint(f);
  unsigned r = (u + 0x7FFFu + ((u >> 16) & 1u)) >> 16;
  return (ushort_t)r;
}

__device__ __forceinline__ int mbcnt64(u64 m){
  return __builtin_amdgcn_mbcnt_hi((unsigned)(m >> 32),
         __builtin_amdgcn_mbcnt_lo((unsigned)m, 0));
}

__device__ __forceinline__ void statadd(u64* SP, int O, int ch, int o, float s, float s2){
  atomicAdd(&SP[(size_t)ch*2*O + o],     (u64)(long long)llrintf(s  * FXSCALE));
  atomicAdd(&SP[(size_t)ch*2*O + O + o], (u64)(long long)llrintf(s2 * FXSCALE));
}

// ---------- transpose [B,C,N]->[B,N,C] + per-point sum of squares (C=3 paths) ----------
__global__ void k_transq(const float* __restrict__ src, long bs, int C,
                         float* __restrict__ xt, float* __restrict__ xx)
{
  int g = blockIdx.x*256 + threadIdx.x;
  if (g >= BN_*NN) return;
  int b = g >> 10, n = g & 1023;
  const float* s = src + (long)b*bs + n;
  float* d = xt + (long)g*C;
  float ss = 0.f;
  for (int c = 0; c < C; ++c){ float v = s[(long)c*NN]; d[c] = v; ss += v*v; }
  xx[g] = ss;
}

// ---------- fused pairwise-dist (float4 loads) + top-20 radix-select ----------
__global__ __launch_bounds__(256) void k_knn(
    const float* __restrict__ X, long bsX,
    const float* __restrict__ XT, const float* __restrict__ XX,
    int* __restrict__ IDX, int C)
{
  extern __shared__ float sm[];          // xi for block's 8 rows: [8*C]
  int tid = threadIdx.x;
  int wave = tid >> 6, lane = tid & 63;
  int b = blockIdx.x >> 7;
  int i0 = (blockIdx.x & 127) << 3;
  for (int t = tid; t < 8*C; t += 256){
    int rr = t / C, cc = t - rr*C;
    sm[t] = XT[((long)(b<<10) + i0 + rr)*C + cc];
  }
  __syncthreads();
  const float* xb = X + (long)b*bsX;
  float acc[2][16];
  #pragma unroll
  for (int r=0;r<2;r++)
    #pragma unroll
    for (int q=0;q<16;q++) acc[r][q]=0.f;
  const float* xi = sm + (wave*2)*C;
  for (int c = 0; c < C; ++c){
    const float4* xr4 = (const float4*)(xb + (long)c*NN);
    float4 xv4[4];
    #pragma unroll
    for (int q4=0;q4<4;q4++) xv4[q4] = xr4[q4*64 + lane];
    #pragma unroll
    for (int r=0;r<2;r++){
      float xiv = xi[r*C + c];
      #pragma unroll
      for (int q4=0;q4<4;q4++){
        acc[r][q4*4+0] = fmaf(xiv, xv4[q4].x, acc[r][q4*4+0]);
        acc[r][q4*4+1] = fmaf(xiv, xv4[q4].y, acc[r][q4*4+1]);
        acc[r][q4*4+2] = fmaf(xiv, xv4[q4].z, acc[r][q4*4+2]);
        acc[r][q4*4+3] = fmaf(xiv, xv4[q4].w, acc[r][q4*4+3]);
      }
    }
  }
  const float4* xx4 = (const float4*)(XX + (b<<10));
  float xxj[16];
  #pragma unroll
  for (int q4=0;q4<4;q4++){
    float4 t = xx4[q4*64 + lane];
    xxj[q4*4+0]=t.x; xxj[q4*4+1]=t.y; xxj[q4*4+2]=t.z; xxj[q4*4+3]=t.w;
  }
  const float* xxb = XX + (b<<10);
  int row0 = i0 + wave*2;
  #pragma unroll
  for (int r=0;r<2;r++){
    float xxi = xxb[row0 + r];
    #pragma unroll
    for (int q=0;q<16;q++) acc[r][q] = 2.f*acc[r][q] - xxi - xxj[q];
  }

  for (int r=0;r<2;r++){
    unsigned u[16];
    #pragma unroll
    for (int q=0;q<16;q++) u[q] = fmap(acc[r][q]);
    unsigned P = 0;
    for (int bit = 31; bit >= 0; --bit){
      unsigned cand = P | (1u << bit);
      int c = 0;
      #pragma unroll
      for (int q=0;q<16;q++) c += (int)__popcll(__ballot(u[q] >= cand));
      if (c >= KK) P = cand;
    }
    int nG = 0;
    #pragma unroll
    for (int q=0;q<16;q++) nG += (int)__popcll(__ballot(u[q] > P));
    int navail = KK - nG;
    int slot = 0;
    int outb = ((b<<10) + row0 + r)*KK;
    #pragma unroll
    for (int q=0;q<16;q++){
      u64 mg = __ballot(u[q] > P);
      u64 me = __ballot(u[q] == P);
      int cg = (int)__popcll(mg);
      int ce = (int)__popcll(me);
      int take_e = navail < ce ? navail : ce;
      int nval = ((q >> 2) << 8) + (lane << 2) + (q & 3);
      if (u[q] > P){
        IDX[outb + slot + mbcnt64(mg)] = nval;
      } else if (u[q] == P){
        int rk = mbcnt64(me);
        if (rk < take_e) IDX[outb + slot + cg + rk] = nval;
      }
      slot += cg + take_e;
      navail -= take_e;
    }
  }
}

// ---------- old-style edge-conv for C=3 layers: writes coalesced YMT[bn][o] ----------
__global__ void k_edgeconv3(const float* __restrict__ XT, const int* __restrict__ IDX,
                            const float* __restrict__ W, float* __restrict__ YMT,
                            u64* __restrict__ SP)
{
  __shared__ float nb[KK*3];
  __shared__ float ctr[3];
  __shared__ int is[KK];
  const int C = 3, O = 64;
  int tid = threadIdx.x;
  int bn = blockIdx.x;
  int b = bn >> 10;
  if (tid < KK) is[tid] = IDX[bn*KK + tid];
  __syncthreads();
  if (tid < 60){ int k = tid/3, c = tid - k*3; nb[tid] = XT[((long)(b<<10)+is[k])*C + c]; }
  if (tid < 3) ctr[tid] = XT[(long)bn*C + tid];
  __syncthreads();
  int o = tid;
  const float* wp = W + (long)o*2*C;
  float yc = 0.f;
  #pragma unroll
  for (int c = 0; c < 3; ++c) yc = fmaf(wp[C+c] - wp[c], ctr[c], yc);
  float acc[KK];
  #pragma unroll
  for (int k=0;k<KK;k++) acc[k] = yc;
  #pragma unroll
  for (int c = 0; c < 3; ++c){
    float wf = wp[c];
    #pragma unroll
    for (int k=0;k<KK;k++) acc[k] = fmaf(wf, nb[k*3+c], acc[k]);
  }
  float mx = -INFINITY, s = 0.f, s2 = 0.f;
  #pragma unroll
  for (int k=0;k<KK;k++){ float v = acc[k]; mx = fmaxf(mx, v); s += v; s2 = fmaf(v,v,s2); }
  YMT[(long)bn*O + o] = mx;
  statadd(SP, O, bn & 63, o, s, s2);
}

// ---------- dense per-point GEMM: AB[bn][2O] = [Wf@x ; (Wc-Wf)@x] ----------
template<int C, int O>
__global__ __launch_bounds__(256) void k_gemm_ab(
    const float* __restrict__ XT, const float* __restrict__ WP,
    float* __restrict__ AB)
{
  constexpr int P = 16;
  constexpr int TWO = 2*O;
  constexpr int CO = (TWO + 255)/256;
  __shared__ __align__(16) float Xs[P][C];
  int tid = threadIdx.x;
  long bn0 = (long)blockIdx.x * P;
  for (int t = tid; t < P*C; t += 256) (&Xs[0][0])[t] = XT[bn0*C + t];
  __syncthreads();
  float acc[CO][P];
  #pragma unroll
  for (int j=0;j<CO;j++)
    #pragma unroll
    for (int r=0;r<P;r++) acc[j][r] = 0.f;
  for (int c4 = 0; c4 < C/4; ++c4){
    float4 w[CO];
    #pragma unroll
    for (int j=0;j<CO;j++){
      int o = tid + j*256;
      if (o < TWO) w[j] = *(const float4*)(WP + ((size_t)c4*TWO + o)*4);
    }
    #pragma unroll
    for (int r=0;r<P;r++){
      float4 xv = *(const float4*)(&Xs[r][c4*4]);
      #pragma unroll
      for (int j=0;j<CO;j++){
        acc[j][r] = fmaf(w[j].x, xv.x, acc[j][r]);
        acc[j][r] = fmaf(w[j].y, xv.y, acc[j][r]);
        acc[j][r] = fmaf(w[j].z, xv.z, acc[j][r]);
        acc[j][r] = fmaf(w[j].w, xv.w, acc[j][r]);
      }
    }
  }
  #pragma unroll
  for (int j=0;j<CO;j++){
    int o = tid + j*256;
    if (o < TWO)
      for (int r=0;r<P;r++) AB[(bn0 + r)*TWO + o] = acc[j][r];
  }
}

// ---------- gather-reduce: y = A[idx] + B[n]; max/sum/sumsq over k ----------
template<int O, int P>
__global__ __launch_bounds__(256) void k_egather(
    const float* __restrict__ AB, const int* __restrict__ IDX,
    float* __restrict__ YMT, u64* __restrict__ SP)
{
  constexpr int TWO = 2*O;
  constexpr int S = 256/O;
  constexpr int PS = P/S;
  __shared__ int is[P][KK];
  int tid = threadIdx.x;
  long bn0 = (long)blockIdx.x * P;
  long b10 = (bn0 >> 10) << 10;
  for (int t = tid; t < P*KK; t += 256) (&is[0][0])[t] = IDX[bn0*KK + t];
  __syncthreads();
  int strand = tid / O;
  int o = tid - strand*O;
  float s = 0.f, s2 = 0.f;
  #pragma unroll
  for (int ps = 0; ps < PS; ++ps){
    int p = strand*PS + ps;
    long bn = bn0 + p;
    float bv = AB[bn*TWO + O + o];
    float mx = -INFINITY;
    #pragma unroll
    for (int k = 0; k < KK; ++k){
      long row = b10 + is[p][k];
      float v = AB[row*TWO + o] + bv;
      mx = fmaxf(mx, v);
      s += v; s2 = fmaf(v,v,s2);
    }
    YMT[bn*O + o] = mx;
  }
  int ch = ((int)blockIdx.x * S + strand) & 63;
  statadd(SP, O, ch, o, s, s2);
}

// ---------- stats finalize: mean + invstd (fixed-order integer sum: exact) ----------
__global__ void k_bnfin(const u64* __restrict__ SP, float* __restrict__ MV, int O, float cnt)
{
  int o = blockIdx.x*blockDim.x + threadIdx.x;
  if (o >= O) return;
  long long S = 0, S2 = 0;
  for (int ch = 0; ch < 64; ++ch){
    S  += (long long)SP[(size_t)ch*2*O + o];
    S2 += (long long)SP[(size_t)ch*2*O + O + o];
  }
  double m = (double)S / ((double)FXSCALE * (double)cnt);
  double ms2 = (double)S2 / ((double)FXSCALE * (double)cnt);
  double var = ms2 - m*m;
  MV[o] = (float)m;
  MV[O + o] = (float)(1.0 / sqrt(var + (double)EPSBN));
}

// ---------- t-net conv2 (recompute conv1 in LDS), RO=2, b128 h1 reads ----------
__global__ __launch_bounds__(64) void k_tconv2(
    const float* __restrict__ XT, const int* __restrict__ IDX,
    const float* __restrict__ W1, const float* __restrict__ MV1,
    const float* __restrict__ W2T, float* __restrict__ M2T, u64* __restrict__ SP)
{
  __shared__ float nb[KK*3];
  __shared__ float ctr[3];
  __shared__ __align__(16) float h1t[64*KK];   // [o][k]
  __shared__ int is[KK];
  int tid = threadIdx.x;               // 64
  int bn = blockIdx.x;
  int b = bn >> 10;
  if (tid < KK) is[tid] = IDX[bn*KK + tid];
  __syncthreads();
  if (tid < 60){ int k = tid/3, c = tid - k*3; nb[tid] = XT[((long)(b<<10)+is[k])*3 + c]; }
  if (tid < 3) ctr[tid] = XT[(long)bn*3 + tid];
  __syncthreads();
  {
    const float* wp = W1 + tid*6;
    float w0=wp[0], w1=wp[1], w2=wp[2];
    float cterm = fmaf(wp[3]-w0, ctr[0], fmaf(wp[4]-w1, ctr[1], (wp[5]-w2)*ctr[2]));
    float m = MV1[tid], iv = MV1[64+tid];
    #pragma unroll
    for (int k=0;k<KK;k++){
      float y = cterm;
      y = fmaf(w0, nb[k*3],   y);
      y = fmaf(w1, nb[k*3+1], y);
      y = fmaf(w2, nb[k*3+2], y);
      h1t[tid*KK + k] = lrelu((y - m) * iv);
    }
  }
  __syncthreads();
  float acc[2][KK];
  #pragma unroll
  for (int j=0;j<2;j++)
    #pragma unroll
    for (int k=0;k<KK;k++) acc[j][k]=0.f;
  #pragma unroll 2
  for (int c=0;c<64;++c){
    float wv0 = W2T[c*128 + tid];
    float wv1 = W2T[c*128 + 64 + tid];
    const float4* hp = (const float4*)(h1t + c*KK);
    float hv[KK];
    #pragma unroll
    for (int q=0;q<5;q++){
      float4 v4 = hp[q];
      hv[q*4]=v4.x; hv[q*4+1]=v4.y; hv[q*4+2]=v4.z; hv[q*4+3]=v4.w;
    }
    #pragma unroll
    for (int k=0;k<KK;k++){
      acc[0][k] = fmaf(wv0, hv[k], acc[0][k]);
      acc[1][k] = fmaf(wv1, hv[k], acc[1][k]);
    }
  }
  int ch = bn & 63;
  #pragma unroll
  for (int j=0;j<2;j++){
    int o = tid + j*64;
    float mx=-INFINITY, s=0.f, s2=0.f;
    #pragma unroll
    for (int k=0;k<KK;k++){ float v = acc[j][k]; mx = fmaxf(mx, v); s += v; s2 = fmaf(v,v,s2); }
    M2T[(long)bn*128 + o] = mx;
    statadd(SP, 128, ch, o, s, s2);
  }
}

// ---------- BN+lrelu from [bn][O] -> [b][*][n] dst (+ optional XT/xx + bf16 XB row) ----------
__global__ __launch_bounds__(256) void k_apply_t(
    const float* __restrict__ SRC, const float* __restrict__ MV,
    int O, float* __restrict__ DST, long dbs, int choff,
    float* __restrict__ XTN, float* __restrict__ XXN,
    ushort_t* __restrict__ XB)
{
  int bn = blockIdx.x*256 + threadIdx.x;
  if (bn >= BN_*NN) return;
  int b = bn >> 10, n = bn & 1023;
  const float4* src = (const float4*)(SRC + (long)bn*O);
  float4* xo = XTN ? (float4*)(XTN + (long)bn*O) : nullptr;
  u64* xbw = XB ? (u64*)(XB + (size_t)bn*512 + choff) : nullptr;
  float ss = 0.f;
  for (int o4 = 0; o4 < O/4; ++o4){
    float4 v = src[o4];
    float vv[4] = {v.x, v.y, v.z, v.w};
    float rr[4];
    #pragma unroll
    for (int u=0;u<4;u++){
      int o = o4*4+u;
      float t = lrelu((vv[u] - MV[o]) * MV[O+o]);
      rr[u] = t;
      ss = fmaf(t,t,ss);
      DST[(long)b*dbs + (long)(choff+o)*NN + n] = t;
    }
    if (xo) xo[o4] = make_float4(rr[0],rr[1],rr[2],rr[3]);
    if (xbw){
      u64 pk = (u64)f2b(rr[0]) | ((u64)f2b(rr[1]) << 16)
             | ((u64)f2b(rr[2]) << 32) | ((u64)f2b(rr[3]) << 48);
      xbw[o4] = pk;
    }
  }
  if (XXN) XXN[bn] = ss;
}

// ---------- weight transpose [O][C] -> [C][O] ----------
__global__ void k_wprep_t(const float* __restrict__ W, float* __restrict__ WT, int O, int C)
{
  int g = blockIdx.x*256+threadIdx.x;
  if (g >= O*C) return;
  int o = g / C, c = g - o*C;
  WT[(long)c*O + o] = W[g];
}

// ---------- quad weight pack for k_gemm_sm: [1024][C] -> WQ[c][t][4] ----------
__global__ void k_wprep_q(const float* __restrict__ W, float* __restrict__ WQ, int C)
{
  int g = blockIdx.x*256+threadIdx.x;
  if (g >= 1024*C) return;
  int o = g / C, c = g - o*C;
  int j = o >> 8, t = o & 255;
  WQ[((size_t)c*256 + t)*4 + j] = W[g];
}

// ---------- MFMA B-operand pack: w6[1024][512] -> bf16 frags ----------
__global__ void k_wprep_mf(const float* __restrict__ W, ushort_t* __restrict__ WB)
{
  int g = blockIdx.x*256+threadIdx.x;
  if (g >= 1024*512) return;
  int o = g >> 9, c = g & 511;
  int ks = c >> 5, kk = c & 31;
  int l = (kk >> 3)*16 + (o & 15);
  int e = kk & 7;
  WB[(((size_t)(o >> 4)*16 + ks)*64 + l)*8 + e] = f2b(W[g]);
}

// ---------- edge weight prep: [O][2C] -> packed WP [C/4][2O][4] ----------
__global__ void k_wprep_e2(const float* __restrict__ W, float* __restrict__ WP, int O, int C)
{
  int g = blockIdx.x*256+threadIdx.x;
  if (g >= O*C) return;
  int o = g / C, c = g - o*C;
  float wf = W[(long)o*2*C + c];
  float wc = W[(long)o*2*C + C + c];
  size_t base = ((size_t)(c>>2)*(2*O))*4 + (c&3);
  WP[base + (size_t)o*4]       = wf;
  WP[base + (size_t)(O+o)*4]   = wc - wf;
}

// ---------- dense GEMM (R13 proven): RO=4, n-tile 16, scalar X, W depth-2 prefetch ----------
__global__ __launch_bounds__(256, 1) void k_gemm_sm(
    const float* __restrict__ WQ, const float* __restrict__ X,
    long bsX, int C, unsigned* __restrict__ MX, u64* __restrict__ SP)
{
  int tid = threadIdx.x;
  int bt = blockIdx.x;
  int b = bt >> 6;
  int n0 = (bt & 63) << 4;
  const float* xrow = X + (long)b*bsX + n0;
  float acc[4][16];
  #pragma unroll
  for (int j=0;j<4;j++)
    #pragma unroll
    for (int i=0;i<16;i++) acc[j][i]=0.f;
  const float4* wq = (const float4*)WQ;

  auto gemm_step = [&](int cc, float4 wv){
    const float4* xc = (const float4*)(xrow + (size_t)cc*NN);
    float4 xa = xc[0], xb2 = xc[1], xe = xc[2], xf = xc[3];
    float wj[4] = {wv.x, wv.y, wv.z, wv.w};
    #pragma unroll
    for (int j=0;j<4;j++){
      float ww = wj[j];
      acc[j][0]=fmaf(ww,xa.x,acc[j][0]);  acc[j][1]=fmaf(ww,xa.y,acc[j][1]);
      acc[j][2]=fmaf(ww,xa.z,acc[j][2]);  acc[j][3]=fmaf(ww,xa.w,acc[j][3]);
      acc[j][4]=fmaf(ww,xb2.x,acc[j][4]);  acc[j][5]=fmaf(ww,xb2.y,acc[j][5]);
      acc[j][6]=fmaf(ww,xb2.z,acc[j][6]);  acc[j][7]=fmaf(ww,xb2.w,acc[j][7]);
      acc[j][8]=fmaf(ww,xe.x,acc[j][8]);  acc[j][9]=fmaf(ww,xe.y,acc[j][9]);
      acc[j][10]=fmaf(ww,xe.z,acc[j][10]); acc[j][11]=fmaf(ww,xe.w,acc[j][11]);
      acc[j][12]=fmaf(ww,xf.x,acc[j][12]); acc[j][13]=fmaf(ww,xf.y,acc[j][13]);
      acc[j][14]=fmaf(ww,xf.z,acc[j][14]); acc[j][15]=fmaf(ww,xf.w,acc[j][15]);
    }
  };

  float4 w0 = wq[tid];
  float4 w1 = wq[256 + tid];
  for (int c = 0; c < C-2; c += 2){
    float4 p0 = wq[(size_t)(c+2)*256 + tid];
    float4 p1 = wq[(size_t)(c+3)*256 + tid];
    gemm_step(c,   w0);
    gemm_step(c+1, w1);
    w0 = p0; w1 = p1;
  }
  gemm_step(C-2, w0);
  gemm_step(C-1, w1);

  int ch = bt & 63;
  #pragma unroll
  for (int j=0;j<4;j++){
    int o = tid + j*256;
    float mx=-INFINITY, s=0.f, s2=0.f;
    #pragma unroll
    for (int i=0;i<16;i++){ float v=acc[j][i]; mx=fmaxf(mx,v); s+=v; s2=fmaf(v,v,s2); }
    atomicMax(&MX[(b<<10) + o], fmap(mx));
    statadd(SP, 1024, ch, o, s, s2);
  }
}

// ---------- MFMA bf16 GEMM for w6: y^T[n][o] tiles, fused max/stats ----------
__global__ __launch_bounds__(256) void k_gemm_mfma(
    const ushort_t* __restrict__ WB, const ushort_t* __restrict__ XB,
    unsigned* __restrict__ MX, u64* __restrict__ SP)
{
  int tid = threadIdx.x;
  int w = tid >> 6, lane = tid & 63;
  int b = blockIdx.x >> 4;
  int ob = blockIdx.x & 15;
  int otile = ob*4 + w;              // 0..63
  int o0 = otile << 4;
  short8v wfrag[16];
  const short8v* wp = (const short8v*)WB;
  #pragma unroll
  for (int ks=0; ks<16; ++ks)
    wfrag[ks] = wp[((size_t)otile*16 + ks)*64 + lane];

  float mx = -INFINITY, s = 0.f, s2 = 0.f;
  int nbase = blockIdx.y*256;
  for (int nt = 0; nt < 16; ++nt){
    int n0 = nbase + nt*16;
    const short8v* xp = (const short8v*)(XB + ((size_t)(b<<10) + n0 + (lane & 15))*512 + (lane >> 4)*8);
    f32x4 acc = {0.f, 0.f, 0.f, 0.f};
    #pragma unroll
    for (int ks=0; ks<16; ++ks){
      short8v a = xp[ks*4];
      acc = __builtin_amdgcn_mfma_f32_16x16x32_bf16(a, wfrag[ks], acc, 0, 0, 0);
    }
    #pragma unroll
    for (int reg=0; reg<4; ++reg){
      float v = acc[reg];
      mx = fmaxf(mx, v); s += v; s2 = fmaf(v, v, s2);
    }
  }
  #pragma unroll
  for (int off=16; off<=32; off<<=1){
    mx = fmaxf(mx, __shfl_xor(mx, off));
    s += __shfl_xor(s, off);
    s2 += __shfl_xor(s2, off);
  }
  if (lane < 16){
    int o = o0 + lane;
    atomicMax(&MX[(b<<10) + o], fmap(mx));
    int ch = ((blockIdx.x << 2) + w + (blockIdx.y << 4)) & 63;
    statadd(SP, 1024, ch, o, s, s2);
  }
}

// ---------- unmap max + BN + lrelu ----------
__global__ void k_finmax(const unsigned* __restrict__ MX, const float* __restrict__ MV,
                         float* __restrict__ OUT)
{
  int g = blockIdx.x*256+threadIdx.x;
  if (g >= BN_*1024) return;
  int o = g & 1023;
  OUT[g] = lrelu((funmap(MX[g]) - MV[o]) * MV[1024+o]);
}

// ---------- fused FC + batch-BN + lrelu: one wave per feature ----------
__global__ __launch_bounds__(256) void k_fcbn(
    const float* __restrict__ A, const float* __restrict__ W,
    const float* __restrict__ bias, int C, int F, float* __restrict__ Z)
{
  int wv = threadIdx.x >> 6, lane = threadIdx.x & 63;
  int f = blockIdx.x*4 + wv;
  if (f >= F) return;
  const float* w = W + (long)f*C;
  float acc[8];
  #pragma unroll
  for (int b=0;b<8;b++) acc[b]=0.f;
  for (int c = lane; c < C; c += 64){
    float wvv = w[c];
    #pragma unroll
    for (int b=0;b<8;b++) acc[b] = fmaf(wvv, A[b*C + c], acc[b]);
  }
  #pragma unroll
  for (int b=0;b<8;b++){
    #pragma unroll
    for (int off=32; off>0; off>>=1) acc[b] += __shfl_xor(acc[b], off);
  }
  float bs = bias ? bias[f] : 0.f;
  float m = 0.f;
  #pragma unroll
  for (int b=0;b<8;b++){ acc[b] += bs; m += acc[b]; }
  m *= 0.125f;
  float var = 0.f;
  #pragma unroll
  for (int b=0;b<8;b++){ float d = acc[b]-m; var = fmaf(d,d,var); }
  var *= 0.125f;
  float is = rsqrtf(var + EPSBN);
  if (lane < 8) Z[lane*F + f] = lrelu((acc[lane]-m)*is);
}

// ---------- fc3 + bias + eye -> T[8,9], one wave per output ----------
__global__ __launch_bounds__(256) void k_fc3w(
    const float* __restrict__ A, const float* __restrict__ W,
    const float* __restrict__ bias, float* __restrict__ T9)
{
  int g = blockIdx.x*4 + (threadIdx.x >> 6);
  int lane = threadIdx.x & 63;
  if (g >= 72) return;
  int b = g / 9, j = g - b*9;
  const float* a = A + b*256;
  const float* w = W + j*256;
  float s = 0.f;
  for (int c = lane; c < 256; c += 64) s = fmaf(a[c], w[c], s);
  #pragma unroll
  for (int off=32; off>0; off>>=1) s += __shfl_xor(s, off);
  if (lane == 0){
    s += bias[j];
    if (j==0 || j==4 || j==8) s += 1.f;
    T9[g] = s;
  }
}

// ---------- apply 3x3 transform: xtr = T @ x ----------
__global__ void k_tapply(const float* __restrict__ Xin, const float* __restrict__ T9,
                         float* __restrict__ Xtr)
{
  int g = blockIdx.x*256+threadIdx.x;
  if (g >= BN_*3*NN) return;
  int n = g & 1023;
  int i = (g >> 10) % 3;
  int b = g / (3*NN);
  const float* t = T9 + b*9 + i*3;
  const float* xb = Xin + (long)b*3*NN + n;
  Xtr[g] = fmaf(t[0], xb[0], fmaf(t[1], xb[NN], t[2]*xb[2*NN]));
}

extern "C" void kernel_launch(void* const* d_in, const int* in_sizes, int n_in,
                              void* d_out, int out_size, void* d_ws, size_t ws_size,
                              hipStream_t stream)
{
  (void)in_sizes; (void)n_in; (void)out_size;
  const float* x     = (const float*)d_in[0];
  const float* tw1   = (const float*)d_in[1];
  const float* tw2   = (const float*)d_in[2];
  const float* tw3   = (const float*)d_in[3];
  const float* tfc1w = (const float*)d_in[4];
  const float* tfc2w = (const float*)d_in[5];
  const float* tfc2b = (const float*)d_in[6];
  const float* tfc3w = (const float*)d_in[7];
  const float* tfc3b = (const float*)d_in[8];
  const float* w1    = (const float*)d_in[9];
  const float* w2    = (const float*)d_in[10];
  const float* w3    = (const float*)d_in[11];
  const float* w4    = (const float*)d_in[12];
  const float* w6    = (const float*)d_in[13];
  float* out = (float*)d_out;

  char* ws = (char*)d_ws;
  size_t off = 0;
  auto alloc = [&](size_t bytes) -> void* {
    off = (off + 255) & ~(size_t)255;
    void* p = ws + off;
    off += bytes;
    return p;
  };
  auto spb = [](int O){ return (size_t)64*2*O*8; };

  float*    xt   = (float*)alloc((size_t)BN_*NN*128*4);
  float*    xx   = (float*)alloc((size_t)BN_*NN*4);
  int*      idx  = (int*)  alloc((size_t)BN_*NN*KK*4);
  float*    ymt  = (float*)alloc((size_t)BN_*NN*256*4);   // also m2t
  float*    ab   = (float*)alloc((size_t)BN_*NN*512*4);
  float*    xcat = (float*)alloc((size_t)BN_*512*NN*4);
  float*    xtr  = (float*)alloc((size_t)BN_*3*NN*4);
  float*    m2   = (float*)alloc((size_t)BN_*128*NN*4);
  ushort_t* xb16 = (ushort_t*)alloc((size_t)BN_*NN*512*2);
  ushort_t* wb16 = (ushort_t*)alloc((size_t)1024*512*2);
  // --- zero-once region ---
  size_t zoff0 = (off + 255) & ~(size_t)255;
  u64*      sp_e1 = (u64*)alloc(spb(64));
  u64*      sp_tc = (u64*)alloc(spb(128));
  u64*      sp_g1 = (u64*)alloc(spb(1024));
  u64*      sp_L1 = (u64*)alloc(spb(64));
  u64*      sp_L2 = (u64*)alloc(spb(64));
  u64*      sp_L3 = (u64*)alloc(spb(128));
  u64*      sp_L4 = (u64*)alloc(spb(256));
  u64*      sp_g2 = (u64*)alloc(spb(1024));
  unsigned* mxu1  = (unsigned*)alloc((size_t)BN_*1024*4);
  unsigned* mxu2  = (unsigned*)alloc((size_t)BN_*1024*4);
  size_t ztotal = off - zoff0;
  // --- end zero-once region ---
  float*    mv1  = (float*)alloc(2*64*4);
  float*    mv2  = (float*)alloc(2*128*4);
  float*    mv3  = (float*)alloc(2*1024*4);
  float*    mvL  = (float*)alloc(2*256*4);
  float*    mv6  = (float*)alloc(2*1024*4);
  float*    vbuf = (float*)alloc((size_t)BN_*1024*4);
  float*    z1   = (float*)alloc((size_t)BN_*512*4);
  float*    z2   = (float*)alloc((size_t)BN_*256*4);
  float*    T9   = (float*)alloc(72*4);
  float*    wt3q = (float*)alloc((size_t)128*1024*4);
  float*    wt2t = (float*)alloc((size_t)64*128*4);
  float*    w2p  = (float*)alloc((size_t)64*128*4);
  float*    w3p  = (float*)alloc((size_t)64*256*4);
  float*    w4p  = (float*)alloc((size_t)128*512*4);
  if (off > ws_size) return;

  float* m2t = ymt;

  const float CNTK = 8.f*1024.f*20.f;
  const float CNTN = 8.f*1024.f;

  hipMemsetAsync((char*)ws + zoff0, 0, ztotal, stream);

  // ===== weight prep =====
  k_wprep_t<<<(128*64+255)/256, 256, 0, stream>>>(tw2, wt2t, 128, 64);
  k_wprep_q<<<(1024*128)/256, 256, 0, stream>>>(tw3, wt3q, 128);
  k_wprep_mf<<<(1024*512)/256, 256, 0, stream>>>(w6, wb16);
  k_wprep_e2<<<(64*64+255)/256, 256, 0, stream>>>(w2, w2p, 64, 64);
  k_wprep_e2<<<(128*64+255)/256, 256, 0, stream>>>(w3, w3p, 128, 64);
  k_wprep_e2<<<(256*128+255)/256, 256, 0, stream>>>(w4, w4p, 256, 128);

  // ===== transform net =====
  k_transq<<<32, 256, 0, stream>>>(x, 3L*NN, 3, xt, xx);
  k_knn<<<1024, 256, 8*3*4, stream>>>(x, 3L*NN, xt, xx, idx, 3);
  k_edgeconv3<<<BN_*NN, 64, 0, stream>>>(xt, idx, tw1, ymt, sp_e1);
  k_bnfin<<<1, 64, 0, stream>>>(sp_e1, mv1, 64, CNTK);
  k_tconv2<<<BN_*NN, 64, 0, stream>>>(xt, idx, tw1, mv1, wt2t, m2t, sp_tc);
  k_bnfin<<<2, 64, 0, stream>>>(sp_tc, mv2, 128, CNTK);
  k_apply_t<<<32, 256, 0, stream>>>(m2t, mv2, 128, m2, 128L*NN, 0, nullptr, nullptr, nullptr);
  k_gemm_sm<<<BN_*64, 256, 0, stream>>>(wt3q, m2, 128L*NN, 128, mxu1, sp_g1);
  k_bnfin<<<16, 64, 0, stream>>>(sp_g1, mv3, 1024, CNTN);
  k_finmax<<<32, 256, 0, stream>>>(mxu1, mv3, vbuf);
  k_fcbn<<<128, 256, 0, stream>>>(vbuf, tfc1w, nullptr, 1024, 512, z1);
  k_fcbn<<<64, 256, 0, stream>>>(z1, tfc2w, tfc2b, 512, 256, z2);
  k_fc3w<<<18, 256, 0, stream>>>(z2, tfc3w, tfc3b, T9);
  k_tapply<<<(BN_*3*NN)/256, 256, 0, stream>>>(x, T9, xtr);

  // ===== edge conv stack =====
  k_transq<<<32, 256, 0, stream>>>(xtr, 3L*NN, 3, xt, xx);
  k_knn<<<1024, 256, 8*3*4, stream>>>(xtr, 3L*NN, xt, xx, idx, 3);
  k_edgeconv3<<<BN_*NN, 64, 0, stream>>>(xt, idx, w1, ymt, sp_L1);
  k_bnfin<<<1, 64, 0, stream>>>(sp_L1, mvL, 64, CNTK);
  k_apply_t<<<32, 256, 0, stream>>>(ymt, mvL, 64, xcat, 512L*NN, 0, xt, xx, xb16);
  // L2
  k_knn<<<1024, 256, 8*64*4, stream>>>(xcat, 512L*NN, xt, xx, idx, 64);
  k_gemm_ab<64,64><<<512, 256, 0, stream>>>(xt, w2p, ab);
  k_egather<64,16><<<512, 256, 0, stream>>>(ab, idx, ymt, sp_L2);
  k_bnfin<<<1, 64, 0, stream>>>(sp_L2, mvL, 64, CNTK);
  k_apply_t<<<32, 256, 0, stream>>>(ymt, mvL, 64, xcat, 512L*NN, 64, xt, xx, xb16);
  // L3
  k_knn<<<1024, 256, 8*64*4, stream>>>(xcat + 64L*NN, 512L*NN, xt, xx, idx, 64);
  k_gemm_ab<64,128><<<512, 256, 0, stream>>>(xt, w3p, ab);
  k_egather<128,16><<<512, 256, 0, stream>>>(ab, idx, ymt, sp_L3);
  k_bnfin<<<2, 64, 0, stream>>>(sp_L3, mvL, 128, CNTK);
  k_apply_t<<<32, 256, 0, stream>>>(ymt, mvL, 128, xcat, 512L*NN, 128, xt, xx, xb16);
  // L4
  k_knn<<<1024, 256, 8*128*4, stream>>>(xcat + 128L*NN, 512L*NN, xt, xx, idx, 128);
  k_gemm_ab<128,256><<<512, 256, 0, stream>>>(xt, w4p, ab);
  k_egather<256,16><<<512, 256, 0, stream>>>(ab, idx, ymt, sp_L4);
  k_bnfin<<<4, 64, 0, stream>>>(sp_L4, mvL, 256, CNTK);
  k_apply_t<<<32, 256, 0, stream>>>(ymt, mvL, 256, xcat, 512L*NN, 256, nullptr, nullptr, xb16);

  // ===== final conv w6 via MFMA bf16 + BN + lrelu + max over N =====
  k_gemm_mfma<<<dim3(BN_*16, 4), 256, 0, stream>>>(wb16, xb16, mxu2, sp_g2);
  k_bnfin<<<16, 64, 0, stream>>>(sp_g2, mv6, 1024, CNTN);
  k_finmax<<<32, 256, 0, stream>>>(mxu2, mv6, out);
}

// Round 19
// 821.179 us; speedup vs baseline: 1.3277x; 1.0120x over previous
//
#include <hip/hip_runtime.h>
#include <math.h>

#define BN_ 8
#define NN 1024
#define KK 20
#define EPSBN 1e-5f
#define FXSCALE 1048576.0f   // 2^20 fixed-point scale for deterministic stats

typedef unsigned long long u64;
typedef unsigned short ushort_t;
typedef __attribute__((ext_vector_type(8))) short short8v;   // 8 bf16 (4 VGPRs)
typedef __attribute__((ext_vector_type(4))) float f32x4;     // MFMA acc

__device__ __forceinline__ float lrelu(float x){ return x > 0.f ? x : 0.2f*x; }

__device__ __forceinline__ unsigned fmap(float x){
  unsigned u = __float_as_uint(x);
  return (u & 0x80000000u) ? ~u : (u | 0x80000000u);
}
__device__ __forceinline__ float funmap(unsigned m){
  unsigned u = (m & 0x80000000u) ? (m & 0x7FFFFFFFu) : ~m;
  return __uint_as_float(u);
}
__device__ __forceinline__ ushort_t f2b(float f){   // RNE fp32 -> bf16 bits
  unsigned u = __float_as_uint(f);
  unsigned r = (u + 0x7FFFu + ((u >> 16) & 1u)) >> 16;
  return (ushort_t)r;
}

__device__ __forceinline__ int mbcnt64(u64 m){
  return __builtin_amdgcn_mbcnt_hi((unsigned)(m >> 32),
         __builtin_amdgcn_mbcnt_lo((unsigned)m, 0));
}

__device__ __forceinline__ void statadd(u64* SP, int O, int ch, int o, float s, float s2){
  atomicAdd(&SP[(size_t)ch*2*O + o],     (u64)(long long)llrintf(s  * FXSCALE));
  atomicAdd(&SP[(size_t)ch*2*O + O + o], (u64)(long long)llrintf(s2 * FXSCALE));
}

// ---------- transpose [B,C,N]->[B,N,C] + per-point sum of squares (C=3 paths) ----------
__global__ void k_transq(const float* __restrict__ src, long bs, int C,
                         float* __restrict__ xt, float* __restrict__ xx)
{
  int g = blockIdx.x*256 + threadIdx.x;
  if (g >= BN_*NN) return;
  int b = g >> 10, n = g & 1023;
  const float* s = src + (long)b*bs + n;
  float* d = xt + (long)g*C;
  float ss = 0.f;
  for (int c = 0; c < C; ++c){ float v = s[(long)c*NN]; d[c] = v; ss += v*v; }
  xx[g] = ss;
}

// ---------- fused pairwise-dist (float4 loads) + top-20 radix-select ----------
// XCD swizzle: batch(sb) = blockIdx%8 = hardware XCD -> per-XCD L2 holds one batch's X
__global__ __launch_bounds__(256) void k_knn(
    const float* __restrict__ X, long bsX,
    const float* __restrict__ XT, const float* __restrict__ XX,
    int* __restrict__ IDX, int C)
{
  extern __shared__ float sm[];          // xi for block's 8 rows: [8*C]
  int tid = threadIdx.x;
  int wave = tid >> 6, lane = tid & 63;
  int sb = (blockIdx.x & 7)*128 + (blockIdx.x >> 3);   // bijective, batch = blockIdx%8
  int b = sb >> 7;
  int i0 = (sb & 127) << 3;
  for (int t = tid; t < 8*C; t += 256){
    int rr = t / C, cc = t - rr*C;
    sm[t] = XT[((long)(b<<10) + i0 + rr)*C + cc];
  }
  __syncthreads();
  const float* xb = X + (long)b*bsX;
  float acc[2][16];
  #pragma unroll
  for (int r=0;r<2;r++)
    #pragma unroll
    for (int q=0;q<16;q++) acc[r][q]=0.f;
  const float* xi = sm + (wave*2)*C;
  for (int c = 0; c < C; ++c){
    const float4* xr4 = (const float4*)(xb + (long)c*NN);
    float4 xv4[4];
    #pragma unroll
    for (int q4=0;q4<4;q4++) xv4[q4] = xr4[q4*64 + lane];
    #pragma unroll
    for (int r=0;r<2;r++){
      float xiv = xi[r*C + c];
      #pragma unroll
      for (int q4=0;q4<4;q4++){
        acc[r][q4*4+0] = fmaf(xiv, xv4[q4].x, acc[r][q4*4+0]);
        acc[r][q4*4+1] = fmaf(xiv, xv4[q4].y, acc[r][q4*4+1]);
        acc[r][q4*4+2] = fmaf(xiv, xv4[q4].z, acc[r][q4*4+2]);
        acc[r][q4*4+3] = fmaf(xiv, xv4[q4].w, acc[r][q4*4+3]);
      }
    }
  }
  const float4* xx4 = (const float4*)(XX + (b<<10));
  float xxj[16];
  #pragma unroll
  for (int q4=0;q4<4;q4++){
    float4 t = xx4[q4*64 + lane];
    xxj[q4*4+0]=t.x; xxj[q4*4+1]=t.y; xxj[q4*4+2]=t.z; xxj[q4*4+3]=t.w;
  }
  const float* xxb = XX + (b<<10);
  int row0 = i0 + wave*2;
  #pragma unroll
  for (int r=0;r<2;r++){
    float xxi = xxb[row0 + r];
    #pragma unroll
    for (int q=0;q<16;q++) acc[r][q] = 2.f*acc[r][q] - xxi - xxj[q];
  }

  for (int r=0;r<2;r++){
    unsigned u[16];
    #pragma unroll
    for (int q=0;q<16;q++) u[q] = fmap(acc[r][q]);
    unsigned P = 0;
    for (int bit = 31; bit >= 0; --bit){
      unsigned cand = P | (1u << bit);
      int c = 0;
      #pragma unroll
      for (int q=0;q<16;q++) c += (int)__popcll(__ballot(u[q] >= cand));
      if (c >= KK) P = cand;
    }
    int nG = 0;
    #pragma unroll
    for (int q=0;q<16;q++) nG += (int)__popcll(__ballot(u[q] > P));
    int navail = KK - nG;
    int slot = 0;
    int outb = ((b<<10) + row0 + r)*KK;
    #pragma unroll
    for (int q=0;q<16;q++){
      u64 mg = __ballot(u[q] > P);
      u64 me = __ballot(u[q] == P);
      int cg = (int)__popcll(mg);
      int ce = (int)__popcll(me);
      int take_e = navail < ce ? navail : ce;
      int nval = ((q >> 2) << 8) + (lane << 2) + (q & 3);
      if (u[q] > P){
        IDX[outb + slot + mbcnt64(mg)] = nval;
      } else if (u[q] == P){
        int rk = mbcnt64(me);
        if (rk < take_e) IDX[outb + slot + cg + rk] = nval;
      }
      slot += cg + take_e;
      navail -= take_e;
    }
  }
}

// ---------- old-style edge-conv for C=3 layers: writes coalesced YMT[bn][o] ----------
__global__ void k_edgeconv3(const float* __restrict__ XT, const int* __restrict__ IDX,
                            const float* __restrict__ W, float* __restrict__ YMT,
                            u64* __restrict__ SP)
{
  __shared__ float nb[KK*3];
  __shared__ float ctr[3];
  __shared__ int is[KK];
  const int C = 3, O = 64;
  int tid = threadIdx.x;
  int bn = blockIdx.x;
  int b = bn >> 10;
  if (tid < KK) is[tid] = IDX[bn*KK + tid];
  __syncthreads();
  if (tid < 60){ int k = tid/3, c = tid - k*3; nb[tid] = XT[((long)(b<<10)+is[k])*C + c]; }
  if (tid < 3) ctr[tid] = XT[(long)bn*C + tid];
  __syncthreads();
  int o = tid;
  const float* wp = W + (long)o*2*C;
  float yc = 0.f;
  #pragma unroll
  for (int c = 0; c < 3; ++c) yc = fmaf(wp[C+c] - wp[c], ctr[c], yc);
  float acc[KK];
  #pragma unroll
  for (int k=0;k<KK;k++) acc[k] = yc;
  #pragma unroll
  for (int c = 0; c < 3; ++c){
    float wf = wp[c];
    #pragma unroll
    for (int k=0;k<KK;k++) acc[k] = fmaf(wf, nb[k*3+c], acc[k]);
  }
  float mx = -INFINITY, s = 0.f, s2 = 0.f;
  #pragma unroll
  for (int k=0;k<KK;k++){ float v = acc[k]; mx = fmaxf(mx, v); s += v; s2 = fmaf(v,v,s2); }
  YMT[(long)bn*O + o] = mx;
  statadd(SP, O, bn & 63, o, s, s2);
}

// ---------- dense per-point GEMM: AB[bn][2O] = [Wf@x ; (Wc-Wf)@x] ----------
// XCD swizzle: producer writes batch-b AB through XCD-b's L2 (consumer egather aligned)
template<int C, int O>
__global__ __launch_bounds__(256) void k_gemm_ab(
    const float* __restrict__ XT, const float* __restrict__ WP,
    float* __restrict__ AB)
{
  constexpr int P = 16;
  constexpr int TWO = 2*O;
  constexpr int CO = (TWO + 255)/256;
  __shared__ __align__(16) float Xs[P][C];
  int tid = threadIdx.x;
  int sb = (blockIdx.x & 7)*64 + (blockIdx.x >> 3);    // batch = blockIdx%8
  long bn0 = (long)sb * P;
  for (int t = tid; t < P*C; t += 256) (&Xs[0][0])[t] = XT[bn0*C + t];
  __syncthreads();
  float acc[CO][P];
  #pragma unroll
  for (int j=0;j<CO;j++)
    #pragma unroll
    for (int r=0;r<P;r++) acc[j][r] = 0.f;
  for (int c4 = 0; c4 < C/4; ++c4){
    float4 w[CO];
    #pragma unroll
    for (int j=0;j<CO;j++){
      int o = tid + j*256;
      if (o < TWO) w[j] = *(const float4*)(WP + ((size_t)c4*TWO + o)*4);
    }
    #pragma unroll
    for (int r=0;r<P;r++){
      float4 xv = *(const float4*)(&Xs[r][c4*4]);
      #pragma unroll
      for (int j=0;j<CO;j++){
        acc[j][r] = fmaf(w[j].x, xv.x, acc[j][r]);
        acc[j][r] = fmaf(w[j].y, xv.y, acc[j][r]);
        acc[j][r] = fmaf(w[j].z, xv.z, acc[j][r]);
        acc[j][r] = fmaf(w[j].w, xv.w, acc[j][r]);
      }
    }
  }
  #pragma unroll
  for (int j=0;j<CO;j++){
    int o = tid + j*256;
    if (o < TWO)
      for (int r=0;r<P;r++) AB[(bn0 + r)*TWO + o] = acc[j][r];
  }
}

// ---------- gather-reduce: y = A[idx] + B[n]; max/sum/sumsq over k ----------
// XCD swizzle matches k_gemm_ab: gather hits the producing XCD's L2
template<int O, int P>
__global__ __launch_bounds__(256) void k_egather(
    const float* __restrict__ AB, const int* __restrict__ IDX,
    float* __restrict__ YMT, u64* __restrict__ SP)
{
  constexpr int TWO = 2*O;
  constexpr int S = 256/O;
  constexpr int PS = P/S;
  __shared__ int is[P][KK];
  int tid = threadIdx.x;
  int sb = (blockIdx.x & 7)*64 + (blockIdx.x >> 3);    // batch = blockIdx%8
  long bn0 = (long)sb * P;
  long b10 = (bn0 >> 10) << 10;
  for (int t = tid; t < P*KK; t += 256) (&is[0][0])[t] = IDX[bn0*KK + t];
  __syncthreads();
  int strand = tid / O;
  int o = tid - strand*O;
  float s = 0.f, s2 = 0.f;
  #pragma unroll
  for (int ps = 0; ps < PS; ++ps){
    int p = strand*PS + ps;
    long bn = bn0 + p;
    float bv = AB[bn*TWO + O + o];
    float mx = -INFINITY;
    #pragma unroll
    for (int k = 0; k < KK; ++k){
      long row = b10 + is[p][k];
      float v = AB[row*TWO + o] + bv;
      mx = fmaxf(mx, v);
      s += v; s2 = fmaf(v,v,s2);
    }
    YMT[bn*O + o] = mx;
  }
  int ch = (sb * S + strand) & 63;
  statadd(SP, O, ch, o, s, s2);
}

// ---------- stats finalize: mean + invstd (fixed-order integer sum: exact) ----------
__global__ void k_bnfin(const u64* __restrict__ SP, float* __restrict__ MV, int O, float cnt)
{
  int o = blockIdx.x*blockDim.x + threadIdx.x;
  if (o >= O) return;
  long long S = 0, S2 = 0;
  for (int ch = 0; ch < 64; ++ch){
    S  += (long long)SP[(size_t)ch*2*O + o];
    S2 += (long long)SP[(size_t)ch*2*O + O + o];
  }
  double m = (double)S / ((double)FXSCALE * (double)cnt);
  double ms2 = (double)S2 / ((double)FXSCALE * (double)cnt);
  double var = ms2 - m*m;
  MV[o] = (float)m;
  MV[O + o] = (float)(1.0 / sqrt(var + (double)EPSBN));
}

// ---------- t-net conv2 (recompute conv1 in LDS), RO=2, b128 h1 reads ----------
__global__ __launch_bounds__(64) void k_tconv2(
    const float* __restrict__ XT, const int* __restrict__ IDX,
    const float* __restrict__ W1, const float* __restrict__ MV1,
    const float* __restrict__ W2T, float* __restrict__ M2T, u64* __restrict__ SP)
{
  __shared__ float nb[KK*3];
  __shared__ float ctr[3];
  __shared__ __align__(16) float h1t[64*KK];   // [o][k]
  __shared__ int is[KK];
  int tid = threadIdx.x;               // 64
  int bn = blockIdx.x;
  int b = bn >> 10;
  if (tid < KK) is[tid] = IDX[bn*KK + tid];
  __syncthreads();
  if (tid < 60){ int k = tid/3, c = tid - k*3; nb[tid] = XT[((long)(b<<10)+is[k])*3 + c]; }
  if (tid < 3) ctr[tid] = XT[(long)bn*3 + tid];
  __syncthreads();
  {
    const float* wp = W1 + tid*6;
    float w0=wp[0], w1=wp[1], w2=wp[2];
    float cterm = fmaf(wp[3]-w0, ctr[0], fmaf(wp[4]-w1, ctr[1], (wp[5]-w2)*ctr[2]));
    float m = MV1[tid], iv = MV1[64+tid];
    #pragma unroll
    for (int k=0;k<KK;k++){
      float y = cterm;
      y = fmaf(w0, nb[k*3],   y);
      y = fmaf(w1, nb[k*3+1], y);
      y = fmaf(w2, nb[k*3+2], y);
      h1t[tid*KK + k] = lrelu((y - m) * iv);
    }
  }
  __syncthreads();
  float acc[2][KK];
  #pragma unroll
  for (int j=0;j<2;j++)
    #pragma unroll
    for (int k=0;k<KK;k++) acc[j][k]=0.f;
  #pragma unroll 2
  for (int c=0;c<64;++c){
    float wv0 = W2T[c*128 + tid];
    float wv1 = W2T[c*128 + 64 + tid];
    const float4* hp = (const float4*)(h1t + c*KK);
    float hv[KK];
    #pragma unroll
    for (int q=0;q<5;q++){
      float4 v4 = hp[q];
      hv[q*4]=v4.x; hv[q*4+1]=v4.y; hv[q*4+2]=v4.z; hv[q*4+3]=v4.w;
    }
    #pragma unroll
    for (int k=0;k<KK;k++){
      acc[0][k] = fmaf(wv0, hv[k], acc[0][k]);
      acc[1][k] = fmaf(wv1, hv[k], acc[1][k]);
    }
  }
  int ch = bn & 63;
  #pragma unroll
  for (int j=0;j<2;j++){
    int o = tid + j*64;
    float mx=-INFINITY, s=0.f, s2=0.f;
    #pragma unroll
    for (int k=0;k<KK;k++){ float v = acc[j][k]; mx = fmaxf(mx, v); s += v; s2 = fmaf(v,v,s2); }
    M2T[(long)bn*128 + o] = mx;
    statadd(SP, 128, ch, o, s, s2);
  }
}

// ---------- BN+lrelu from [bn][O] -> [b][*][n] dst (+ optional XT/xx + bf16 XB row) ----------
__global__ __launch_bounds__(256) void k_apply_t(
    const float* __restrict__ SRC, const float* __restrict__ MV,
    int O, float* __restrict__ DST, long dbs, int choff,
    float* __restrict__ XTN, float* __restrict__ XXN,
    ushort_t* __restrict__ XB)
{
  int bn = blockIdx.x*256 + threadIdx.x;
  if (bn >= BN_*NN) return;
  int b = bn >> 10, n = bn & 1023;
  const float4* src = (const float4*)(SRC + (long)bn*O);
  float4* xo = XTN ? (float4*)(XTN + (long)bn*O) : nullptr;
  u64* xbw = XB ? (u64*)(XB + (size_t)bn*512 + choff) : nullptr;
  float ss = 0.f;
  for (int o4 = 0; o4 < O/4; ++o4){
    float4 v = src[o4];
    float vv[4] = {v.x, v.y, v.z, v.w};
    float rr[4];
    #pragma unroll
    for (int u=0;u<4;u++){
      int o = o4*4+u;
      float t = lrelu((vv[u] - MV[o]) * MV[O+o]);
      rr[u] = t;
      ss = fmaf(t,t,ss);
      DST[(long)b*dbs + (long)(choff+o)*NN + n] = t;
    }
    if (xo) xo[o4] = make_float4(rr[0],rr[1],rr[2],rr[3]);
    if (xbw){
      u64 pk = (u64)f2b(rr[0]) | ((u64)f2b(rr[1]) << 16)
             | ((u64)f2b(rr[2]) << 32) | ((u64)f2b(rr[3]) << 48);
      xbw[o4] = pk;
    }
  }
  if (XXN) XXN[bn] = ss;
}

// ---------- weight transpose [O][C] -> [C][O] ----------
__global__ void k_wprep_t(const float* __restrict__ W, float* __restrict__ WT, int O, int C)
{
  int g = blockIdx.x*256+threadIdx.x;
  if (g >= O*C) return;
  int o = g / C, c = g - o*C;
  WT[(long)c*O + o] = W[g];
}

// ---------- quad weight pack for k_gemm_sm: [1024][C] -> WQ[c][t][4] ----------
__global__ void k_wprep_q(const float* __restrict__ W, float* __restrict__ WQ, int C)
{
  int g = blockIdx.x*256+threadIdx.x;
  if (g >= 1024*C) return;
  int o = g / C, c = g - o*C;
  int j = o >> 8, t = o & 255;
  WQ[((size_t)c*256 + t)*4 + j] = W[g];
}

// ---------- MFMA B-operand pack: w6[1024][512] -> bf16 frags ----------
__global__ void k_wprep_mf(const float* __restrict__ W, ushort_t* __restrict__ WB)
{
  int g = blockIdx.x*256+threadIdx.x;
  if (g >= 1024*512) return;
  int o = g >> 9, c = g & 511;
  int ks = c >> 5, kk = c & 31;
  int l = (kk >> 3)*16 + (o & 15);
  int e = kk & 7;
  WB[(((size_t)(o >> 4)*16 + ks)*64 + l)*8 + e] = f2b(W[g]);
}

// ---------- edge weight prep: [O][2C] -> packed WP [C/4][2O][4] ----------
__global__ void k_wprep_e2(const float* __restrict__ W, float* __restrict__ WP, int O, int C)
{
  int g = blockIdx.x*256+threadIdx.x;
  if (g >= O*C) return;
  int o = g / C, c = g - o*C;
  float wf = W[(long)o*2*C + c];
  float wc = W[(long)o*2*C + C + c];
  size_t base = ((size_t)(c>>2)*(2*O))*4 + (c&3);
  WP[base + (size_t)o*4]       = wf;
  WP[base + (size_t)(O+o)*4]   = wc - wf;
}

// ---------- dense GEMM (R13 proven): RO=4, n-tile 16, scalar X, W depth-2 prefetch ----------
__global__ __launch_bounds__(256, 1) void k_gemm_sm(
    const float* __restrict__ WQ, const float* __restrict__ X,
    long bsX, int C, unsigned* __restrict__ MX, u64* __restrict__ SP)
{
  int tid = threadIdx.x;
  int bt = blockIdx.x;
  int b = bt >> 6;
  int n0 = (bt & 63) << 4;
  const float* xrow = X + (long)b*bsX + n0;
  float acc[4][16];
  #pragma unroll
  for (int j=0;j<4;j++)
    #pragma unroll
    for (int i=0;i<16;i++) acc[j][i]=0.f;
  const float4* wq = (const float4*)WQ;

  auto gemm_step = [&](int cc, float4 wv){
    const float4* xc = (const float4*)(xrow + (size_t)cc*NN);
    float4 xa = xc[0], xb2 = xc[1], xe = xc[2], xf = xc[3];
    float wj[4] = {wv.x, wv.y, wv.z, wv.w};
    #pragma unroll
    for (int j=0;j<4;j++){
      float ww = wj[j];
      acc[j][0]=fmaf(ww,xa.x,acc[j][0]);  acc[j][1]=fmaf(ww,xa.y,acc[j][1]);
      acc[j][2]=fmaf(ww,xa.z,acc[j][2]);  acc[j][3]=fmaf(ww,xa.w,acc[j][3]);
      acc[j][4]=fmaf(ww,xb2.x,acc[j][4]);  acc[j][5]=fmaf(ww,xb2.y,acc[j][5]);
      acc[j][6]=fmaf(ww,xb2.z,acc[j][6]);  acc[j][7]=fmaf(ww,xb2.w,acc[j][7]);
      acc[j][8]=fmaf(ww,xe.x,acc[j][8]);  acc[j][9]=fmaf(ww,xe.y,acc[j][9]);
      acc[j][10]=fmaf(ww,xe.z,acc[j][10]); acc[j][11]=fmaf(ww,xe.w,acc[j][11]);
      acc[j][12]=fmaf(ww,xf.x,acc[j][12]); acc[j][13]=fmaf(ww,xf.y,acc[j][13]);
      acc[j][14]=fmaf(ww,xf.z,acc[j][14]); acc[j][15]=fmaf(ww,xf.w,acc[j][15]);
    }
  };

  float4 w0 = wq[tid];
  float4 w1 = wq[256 + tid];
  for (int c = 0; c < C-2; c += 2){
    float4 p0 = wq[(size_t)(c+2)*256 + tid];
    float4 p1 = wq[(size_t)(c+3)*256 + tid];
    gemm_step(c,   w0);
    gemm_step(c+1, w1);
    w0 = p0; w1 = p1;
  }
  gemm_step(C-2, w0);
  gemm_step(C-1, w1);

  int ch = bt & 63;
  #pragma unroll
  for (int j=0;j<4;j++){
    int o = tid + j*256;
    float mx=-INFINITY, s=0.f, s2=0.f;
    #pragma unroll
    for (int i=0;i<16;i++){ float v=acc[j][i]; mx=fmaxf(mx,v); s+=v; s2=fmaf(v,v,s2); }
    atomicMax(&MX[(b<<10) + o], fmap(mx));
    statadd(SP, 1024, ch, o, s, s2);
  }
}

// ---------- MFMA bf16 GEMM for w6: y^T[n][o] tiles, fused max/stats ----------
__global__ __launch_bounds__(256) void k_gemm_mfma(
    const ushort_t* __restrict__ WB, const ushort_t* __restrict__ XB,
    unsigned* __restrict__ MX, u64* __restrict__ SP)
{
  int tid = threadIdx.x;
  int w = tid >> 6, lane = tid & 63;
  int b = blockIdx.x >> 4;
  int ob = blockIdx.x & 15;
  int otile = ob*4 + w;              // 0..63
  int o0 = otile << 4;
  short8v wfrag[16];
  const short8v* wp = (const short8v*)WB;
  #pragma unroll
  for (int ks=0; ks<16; ++ks)
    wfrag[ks] = wp[((size_t)otile*16 + ks)*64 + lane];

  float mx = -INFINITY, s = 0.f, s2 = 0.f;
  int nbase = blockIdx.y*256;
  for (int nt = 0; nt < 16; ++nt){
    int n0 = nbase + nt*16;
    const short8v* xp = (const short8v*)(XB + ((size_t)(b<<10) + n0 + (lane & 15))*512 + (lane >> 4)*8);
    f32x4 acc = {0.f, 0.f, 0.f, 0.f};
    #pragma unroll
    for (int ks=0; ks<16; ++ks){
      short8v a = xp[ks*4];
      acc = __builtin_amdgcn_mfma_f32_16x16x32_bf16(a, wfrag[ks], acc, 0, 0, 0);
    }
    #pragma unroll
    for (int reg=0; reg<4; ++reg){
      float v = acc[reg];
      mx = fmaxf(mx, v); s += v; s2 = fmaf(v, v, s2);
    }
  }
  #pragma unroll
  for (int off=16; off<=32; off<<=1){
    mx = fmaxf(mx, __shfl_xor(mx, off));
    s += __shfl_xor(s, off);
    s2 += __shfl_xor(s2, off);
  }
  if (lane < 16){
    int o = o0 + lane;
    atomicMax(&MX[(b<<10) + o], fmap(mx));
    int ch = ((blockIdx.x << 2) + w + (blockIdx.y << 4)) & 63;
    statadd(SP, 1024, ch, o, s, s2);
  }
}

// ---------- unmap max + BN + lrelu ----------
__global__ void k_finmax(const unsigned* __restrict__ MX, const float* __restrict__ MV,
                         float* __restrict__ OUT)
{
  int g = blockIdx.x*256+threadIdx.x;
  if (g >= BN_*1024) return;
  int o = g & 1023;
  OUT[g] = lrelu((funmap(MX[g]) - MV[o]) * MV[1024+o]);
}

// ---------- fused FC + batch-BN + lrelu: one wave per feature ----------
__global__ __launch_bounds__(256) void k_fcbn(
    const float* __restrict__ A, const float* __restrict__ W,
    const float* __restrict__ bias, int C, int F, float* __restrict__ Z)
{
  int wv = threadIdx.x >> 6, lane = threadIdx.x & 63;
  int f = blockIdx.x*4 + wv;
  if (f >= F) return;
  const float* w = W + (long)f*C;
  float acc[8];
  #pragma unroll
  for (int b=0;b<8;b++) acc[b]=0.f;
  for (int c = lane; c < C; c += 64){
    float wvv = w[c];
    #pragma unroll
    for (int b=0;b<8;b++) acc[b] = fmaf(wvv, A[b*C + c], acc[b]);
  }
  #pragma unroll
  for (int b=0;b<8;b++){
    #pragma unroll
    for (int off=32; off>0; off>>=1) acc[b] += __shfl_xor(acc[b], off);
  }
  float bs = bias ? bias[f] : 0.f;
  float m = 0.f;
  #pragma unroll
  for (int b=0;b<8;b++){ acc[b] += bs; m += acc[b]; }
  m *= 0.125f;
  float var = 0.f;
  #pragma unroll
  for (int b=0;b<8;b++){ float d = acc[b]-m; var = fmaf(d,d,var); }
  var *= 0.125f;
  float is = rsqrtf(var + EPSBN);
  if (lane < 8) Z[lane*F + f] = lrelu((acc[lane]-m)*is);
}

// ---------- fc3 + bias + eye -> T[8,9], one wave per output ----------
__global__ __launch_bounds__(256) void k_fc3w(
    const float* __restrict__ A, const float* __restrict__ W,
    const float* __restrict__ bias, float* __restrict__ T9)
{
  int g = blockIdx.x*4 + (threadIdx.x >> 6);
  int lane = threadIdx.x & 63;
  if (g >= 72) return;
  int b = g / 9, j = g - b*9;
  const float* a = A + b*256;
  const float* w = W + j*256;
  float s = 0.f;
  for (int c = lane; c < 256; c += 64) s = fmaf(a[c], w[c], s);
  #pragma unroll
  for (int off=32; off>0; off>>=1) s += __shfl_xor(s, off);
  if (lane == 0){
    s += bias[j];
    if (j==0 || j==4 || j==8) s += 1.f;
    T9[g] = s;
  }
}

// ---------- apply 3x3 transform: xtr = T @ x ----------
__global__ void k_tapply(const float* __restrict__ Xin, const float* __restrict__ T9,
                         float* __restrict__ Xtr)
{
  int g = blockIdx.x*256+threadIdx.x;
  if (g >= BN_*3*NN) return;
  int n = g & 1023;
  int i = (g >> 10) % 3;
  int b = g / (3*NN);
  const float* t = T9 + b*9 + i*3;
  const float* xb = Xin + (long)b*3*NN + n;
  Xtr[g] = fmaf(t[0], xb[0], fmaf(t[1], xb[NN], t[2]*xb[2*NN]));
}

extern "C" void kernel_launch(void* const* d_in, const int* in_sizes, int n_in,
                              void* d_out, int out_size, void* d_ws, size_t ws_size,
                              hipStream_t stream)
{
  (void)in_sizes; (void)n_in; (void)out_size;
  const float* x     = (const float*)d_in[0];
  const float* tw1   = (const float*)d_in[1];
  const float* tw2   = (const float*)d_in[2];
  const float* tw3   = (const float*)d_in[3];
  const float* tfc1w = (const float*)d_in[4];
  const float* tfc2w = (const float*)d_in[5];
  const float* tfc2b = (const float*)d_in[6];
  const float* tfc3w = (const float*)d_in[7];
  const float* tfc3b = (const float*)d_in[8];
  const float* w1    = (const float*)d_in[9];
  const float* w2    = (const float*)d_in[10];
  const float* w3    = (const float*)d_in[11];
  const float* w4    = (const float*)d_in[12];
  const float* w6    = (const float*)d_in[13];
  float* out = (float*)d_out;

  char* ws = (char*)d_ws;
  size_t off = 0;
  auto alloc = [&](size_t bytes) -> void* {
    off = (off + 255) & ~(size_t)255;
    void* p = ws + off;
    off += bytes;
    return p;
  };
  auto spb = [](int O){ return (size_t)64*2*O*8; };

  float*    xt   = (float*)alloc((size_t)BN_*NN*128*4);
  float*    xx   = (float*)alloc((size_t)BN_*NN*4);
  int*      idx  = (int*)  alloc((size_t)BN_*NN*KK*4);
  float*    ymt  = (float*)alloc((size_t)BN_*NN*256*4);   // also m2t
  float*    ab   = (float*)alloc((size_t)BN_*NN*512*4);
  float*    xcat = (float*)alloc((size_t)BN_*512*NN*4);
  float*    xtr  = (float*)alloc((size_t)BN_*3*NN*4);
  float*    m2   = (float*)alloc((size_t)BN_*128*NN*4);
  ushort_t* xb16 = (ushort_t*)alloc((size_t)BN_*NN*512*2);
  ushort_t* wb16 = (ushort_t*)alloc((size_t)1024*512*2);
  // --- zero-once region ---
  size_t zoff0 = (off + 255) & ~(size_t)255;
  u64*      sp_e1 = (u64*)alloc(spb(64));
  u64*      sp_tc = (u64*)alloc(spb(128));
  u64*      sp_g1 = (u64*)alloc(spb(1024));
  u64*      sp_L1 = (u64*)alloc(spb(64));
  u64*      sp_L2 = (u64*)alloc(spb(64));
  u64*      sp_L3 = (u64*)alloc(spb(128));
  u64*      sp_L4 = (u64*)alloc(spb(256));
  u64*      sp_g2 = (u64*)alloc(spb(1024));
  unsigned* mxu1  = (unsigned*)alloc((size_t)BN_*1024*4);
  unsigned* mxu2  = (unsigned*)alloc((size_t)BN_*1024*4);
  size_t ztotal = off - zoff0;
  // --- end zero-once region ---
  float*    mv1  = (float*)alloc(2*64*4);
  float*    mv2  = (float*)alloc(2*128*4);
  float*    mv3  = (float*)alloc(2*1024*4);
  float*    mvL  = (float*)alloc(2*256*4);
  float*    mv6  = (float*)alloc(2*1024*4);
  float*    vbuf = (float*)alloc((size_t)BN_*1024*4);
  float*    z1   = (float*)alloc((size_t)BN_*512*4);
  float*    z2   = (float*)alloc((size_t)BN_*256*4);
  float*    T9   = (float*)alloc(72*4);
  float*    wt3q = (float*)alloc((size_t)128*1024*4);
  float*    wt2t = (float*)alloc((size_t)64*128*4);
  float*    w2p  = (float*)alloc((size_t)64*128*4);
  float*    w3p  = (float*)alloc((size_t)64*256*4);
  float*    w4p  = (float*)alloc((size_t)128*512*4);
  if (off > ws_size) return;

  float* m2t = ymt;

  const float CNTK = 8.f*1024.f*20.f;
  const float CNTN = 8.f*1024.f;

  hipMemsetAsync((char*)ws + zoff0, 0, ztotal, stream);

  // ===== weight prep =====
  k_wprep_t<<<(128*64+255)/256, 256, 0, stream>>>(tw2, wt2t, 128, 64);
  k_wprep_q<<<(1024*128)/256, 256, 0, stream>>>(tw3, wt3q, 128);
  k_wprep_mf<<<(1024*512)/256, 256, 0, stream>>>(w6, wb16);
  k_wprep_e2<<<(64*64+255)/256, 256, 0, stream>>>(w2, w2p, 64, 64);
  k_wprep_e2<<<(128*64+255)/256, 256, 0, stream>>>(w3, w3p, 128, 64);
  k_wprep_e2<<<(256*128+255)/256, 256, 0, stream>>>(w4, w4p, 256, 128);

  // ===== transform net =====
  k_transq<<<32, 256, 0, stream>>>(x, 3L*NN, 3, xt, xx);
  k_knn<<<1024, 256, 8*3*4, stream>>>(x, 3L*NN, xt, xx, idx, 3);
  k_edgeconv3<<<BN_*NN, 64, 0, stream>>>(xt, idx, tw1, ymt, sp_e1);
  k_bnfin<<<1, 64, 0, stream>>>(sp_e1, mv1, 64, CNTK);
  k_tconv2<<<BN_*NN, 64, 0, stream>>>(xt, idx, tw1, mv1, wt2t, m2t, sp_tc);
  k_bnfin<<<2, 64, 0, stream>>>(sp_tc, mv2, 128, CNTK);
  k_apply_t<<<32, 256, 0, stream>>>(m2t, mv2, 128, m2, 128L*NN, 0, nullptr, nullptr, nullptr);
  k_gemm_sm<<<BN_*64, 256, 0, stream>>>(wt3q, m2, 128L*NN, 128, mxu1, sp_g1);
  k_bnfin<<<16, 64, 0, stream>>>(sp_g1, mv3, 1024, CNTN);
  k_finmax<<<32, 256, 0, stream>>>(mxu1, mv3, vbuf);
  k_fcbn<<<128, 256, 0, stream>>>(vbuf, tfc1w, nullptr, 1024, 512, z1);
  k_fcbn<<<64, 256, 0, stream>>>(z1, tfc2w, tfc2b, 512, 256, z2);
  k_fc3w<<<18, 256, 0, stream>>>(z2, tfc3w, tfc3b, T9);
  k_tapply<<<(BN_*3*NN)/256, 256, 0, stream>>>(x, T9, xtr);

  // ===== edge conv stack =====
  k_transq<<<32, 256, 0, stream>>>(xtr, 3L*NN, 3, xt, xx);
  k_knn<<<1024, 256, 8*3*4, stream>>>(xtr, 3L*NN, xt, xx, idx, 3);
  k_edgeconv3<<<BN_*NN, 64, 0, stream>>>(xt, idx, w1, ymt, sp_L1);
  k_bnfin<<<1, 64, 0, stream>>>(sp_L1, mvL, 64, CNTK);
  k_apply_t<<<32, 256, 0, stream>>>(ymt, mvL, 64, xcat, 512L*NN, 0, xt, xx, xb16);
  // L2
  k_knn<<<1024, 256, 8*64*4, stream>>>(xcat, 512L*NN, xt, xx, idx, 64);
  k_gemm_ab<64,64><<<512, 256, 0, stream>>>(xt, w2p, ab);
  k_egather<64,16><<<512, 256, 0, stream>>>(ab, idx, ymt, sp_L2);
  k_bnfin<<<1, 64, 0, stream>>>(sp_L2, mvL, 64, CNTK);
  k_apply_t<<<32, 256, 0, stream>>>(ymt, mvL, 64, xcat, 512L*NN, 64, xt, xx, xb16);
  // L3
  k_knn<<<1024, 256, 8*64*4, stream>>>(xcat + 64L*NN, 512L*NN, xt, xx, idx, 64);
  k_gemm_ab<64,128><<<512, 256, 0, stream>>>(xt, w3p, ab);
  k_egather<128,16><<<512, 256, 0, stream>>>(ab, idx, ymt, sp_L3);
  k_bnfin<<<2, 64, 0, stream>>>(sp_L3, mvL, 128, CNTK);
  k_apply_t<<<32, 256, 0, stream>>>(ymt, mvL, 128, xcat, 512L*NN, 128, xt, xx, xb16);
  // L4
  k_knn<<<1024, 256, 8*128*4, stream>>>(xcat + 128L*NN, 512L*NN, xt, xx, idx, 128);
  k_gemm_ab<128,256><<<512, 256, 0, stream>>>(xt, w4p, ab);
  k_egather<256,16><<<512, 256, 0, stream>>>(ab, idx, ymt, sp_L4);
  k_bnfin<<<4, 64, 0, stream>>>(sp_L4, mvL, 256, CNTK);
  k_apply_t<<<32, 256, 0, stream>>>(ymt, mvL, 256, xcat, 512L*NN, 256, nullptr, nullptr, xb16);

  // ===== final conv w6 via MFMA bf16 + BN + lrelu + max over N =====
  k_gemm_mfma<<<dim3(BN_*16, 4), 256, 0, stream>>>(wb16, xb16, mxu2, sp_g2);
  k_bnfin<<<16, 64, 0, stream>>>(sp_g2, mv6, 1024, CNTN);
  k_finmax<<<32, 256, 0, stream>>>(mxu2, mv6, out);
}

// Round 20
// 783.208 us; speedup vs baseline: 1.3920x; 1.0485x over previous
//
#include <hip/hip_runtime.h>
#include <math.h>

#define BN_ 8
#define NN 1024
#define KK 20
#define EPSBN 1e-5f
#define FXSCALE 1048576.0f   // 2^20 fixed-point scale for deterministic stats

typedef unsigned long long u64;
typedef unsigned short ushort_t;
typedef __attribute__((ext_vector_type(8))) short short8v;   // 8 bf16 (4 VGPRs)
typedef __attribute__((ext_vector_type(4))) float f32x4;     // MFMA acc

__device__ __forceinline__ float lrelu(float x){ return x > 0.f ? x : 0.2f*x; }

__device__ __forceinline__ unsigned fmap(float x){
  unsigned u = __float_as_uint(x);
  return (u & 0x80000000u) ? ~u : (u | 0x80000000u);
}
__device__ __forceinline__ float funmap(unsigned m){
  unsigned u = (m & 0x80000000u) ? (m & 0x7FFFFFFFu) : ~m;
  return __uint_as_float(u);
}
__device__ __forceinline__ ushort_t f2b(float f){   // RNE fp32 -> bf16 bits
  unsigned u = __float_as_uint(f);
  unsigned r = (u + 0x7FFFu + ((u >> 16) & 1u)) >> 16;
  return (ushort_t)r;
}

__device__ __forceinline__ int mbcnt64(u64 m){
  return __builtin_amdgcn_mbcnt_hi((unsigned)(m >> 32),
         __builtin_amdgcn_mbcnt_lo((unsigned)m, 0));
}

__device__ __forceinline__ void statadd(u64* SP, int O, int ch, int o, float s, float s2){
  atomicAdd(&SP[(size_t)ch*2*O + o],     (u64)(long long)llrintf(s  * FXSCALE));
  atomicAdd(&SP[(size_t)ch*2*O + O + o], (u64)(long long)llrintf(s2 * FXSCALE));
}

// ---------- transpose [B,C,N]->[B,N,C] + per-point sum of squares (C=3 paths) ----------
__global__ void k_transq(const float* __restrict__ src, long bs, int C,
                         float* __restrict__ xt, float* __restrict__ xx)
{
  int g = blockIdx.x*256 + threadIdx.x;
  if (g >= BN_*NN) return;
  int b = g >> 10, n = g & 1023;
  const float* s = src + (long)b*bs + n;
  float* d = xt + (long)g*C;
  float ss = 0.f;
  for (int c = 0; c < C; ++c){ float v = s[(long)c*NN]; d[c] = v; ss += v*v; }
  xx[g] = ss;
}

// ---------- fused pairwise-dist (float4 loads) + top-20 radix-select (early-exit) ----------
__global__ __launch_bounds__(256) void k_knn(
    const float* __restrict__ X, long bsX,
    const float* __restrict__ XT, const float* __restrict__ XX,
    int* __restrict__ IDX, int C)
{
  extern __shared__ float sm[];          // xi for block's 8 rows: [8*C]
  int tid = threadIdx.x;
  int wave = tid >> 6, lane = tid & 63;
  int sb = (blockIdx.x & 7)*128 + (blockIdx.x >> 3);   // bijective, batch = blockIdx%8
  int b = sb >> 7;
  int i0 = (sb & 127) << 3;
  for (int t = tid; t < 8*C; t += 256){
    int rr = t / C, cc = t - rr*C;
    sm[t] = XT[((long)(b<<10) + i0 + rr)*C + cc];
  }
  __syncthreads();
  const float* xb = X + (long)b*bsX;
  float acc[2][16];
  #pragma unroll
  for (int r=0;r<2;r++)
    #pragma unroll
    for (int q=0;q<16;q++) acc[r][q]=0.f;
  const float* xi = sm + (wave*2)*C;
  for (int c = 0; c < C; ++c){
    const float4* xr4 = (const float4*)(xb + (long)c*NN);
    float4 xv4[4];
    #pragma unroll
    for (int q4=0;q4<4;q4++) xv4[q4] = xr4[q4*64 + lane];
    #pragma unroll
    for (int r=0;r<2;r++){
      float xiv = xi[r*C + c];
      #pragma unroll
      for (int q4=0;q4<4;q4++){
        acc[r][q4*4+0] = fmaf(xiv, xv4[q4].x, acc[r][q4*4+0]);
        acc[r][q4*4+1] = fmaf(xiv, xv4[q4].y, acc[r][q4*4+1]);
        acc[r][q4*4+2] = fmaf(xiv, xv4[q4].z, acc[r][q4*4+2]);
        acc[r][q4*4+3] = fmaf(xiv, xv4[q4].w, acc[r][q4*4+3]);
      }
    }
  }
  const float4* xx4 = (const float4*)(XX + (b<<10));
  float xxj[16];
  #pragma unroll
  for (int q4=0;q4<4;q4++){
    float4 t = xx4[q4*64 + lane];
    xxj[q4*4+0]=t.x; xxj[q4*4+1]=t.y; xxj[q4*4+2]=t.z; xxj[q4*4+3]=t.w;
  }
  const float* xxb = XX + (b<<10);
  int row0 = i0 + wave*2;
  #pragma unroll
  for (int r=0;r<2;r++){
    float xxi = xxb[row0 + r];
    #pragma unroll
    for (int q=0;q<16;q++) acc[r][q] = 2.f*acc[r][q] - xxi - xxj[q];
  }

  for (int r=0;r<2;r++){
    unsigned u[16];
    #pragma unroll
    for (int q=0;q<16;q++) u[q] = fmap(acc[r][q]);
    // bisect for threshold prefix; early-exit when count == KK exactly
    // (top-20 set then fully determined; emission path handles it as
    //  nG strictly-greater + all equals, identical set semantics)
    unsigned P = 0;
    for (int bit = 31; bit >= 0; --bit){
      unsigned cand = P | (1u << bit);
      int c = 0;
      #pragma unroll
      for (int q=0;q<16;q++) c += (int)__popcll(__ballot(u[q] >= cand));
      if (c >= KK){
        P = cand;
        if (c == KK) break;        // wave-uniform scalar branch
      }
    }
    int nG = 0;
    #pragma unroll
    for (int q=0;q<16;q++) nG += (int)__popcll(__ballot(u[q] > P));
    int navail = KK - nG;
    int slot = 0;
    int outb = ((b<<10) + row0 + r)*KK;
    #pragma unroll
    for (int q=0;q<16;q++){
      u64 mg = __ballot(u[q] > P);
      u64 me = __ballot(u[q] == P);
      int cg = (int)__popcll(mg);
      int ce = (int)__popcll(me);
      int take_e = navail < ce ? navail : ce;
      int nval = ((q >> 2) << 8) + (lane << 2) + (q & 3);
      if (u[q] > P){
        IDX[outb + slot + mbcnt64(mg)] = nval;
      } else if (u[q] == P){
        int rk = mbcnt64(me);
        if (rk < take_e) IDX[outb + slot + cg + rk] = nval;
      }
      slot += cg + take_e;
      navail -= take_e;
    }
  }
}

// ---------- old-style edge-conv for C=3 layers: writes coalesced YMT[bn][o] ----------
__global__ void k_edgeconv3(const float* __restrict__ XT, const int* __restrict__ IDX,
                            const float* __restrict__ W, float* __restrict__ YMT,
                            u64* __restrict__ SP)
{
  __shared__ float nb[KK*3];
  __shared__ float ctr[3];
  __shared__ int is[KK];
  const int C = 3, O = 64;
  int tid = threadIdx.x;
  int bn = blockIdx.x;
  int b = bn >> 10;
  if (tid < KK) is[tid] = IDX[bn*KK + tid];
  __syncthreads();
  if (tid < 60){ int k = tid/3, c = tid - k*3; nb[tid] = XT[((long)(b<<10)+is[k])*C + c]; }
  if (tid < 3) ctr[tid] = XT[(long)bn*C + tid];
  __syncthreads();
  int o = tid;
  const float* wp = W + (long)o*2*C;
  float yc = 0.f;
  #pragma unroll
  for (int c = 0; c < 3; ++c) yc = fmaf(wp[C+c] - wp[c], ctr[c], yc);
  float acc[KK];
  #pragma unroll
  for (int k=0;k<KK;k++) acc[k] = yc;
  #pragma unroll
  for (int c = 0; c < 3; ++c){
    float wf = wp[c];
    #pragma unroll
    for (int k=0;k<KK;k++) acc[k] = fmaf(wf, nb[k*3+c], acc[k]);
  }
  float mx = -INFINITY, s = 0.f, s2 = 0.f;
  #pragma unroll
  for (int k=0;k<KK;k++){ float v = acc[k]; mx = fmaxf(mx, v); s += v; s2 = fmaf(v,v,s2); }
  YMT[(long)bn*O + o] = mx;
  statadd(SP, O, bn & 63, o, s, s2);
}

// ---------- dense per-point GEMM: AB[bn][2O] = [Wf@x ; (Wc-Wf)@x] ----------
template<int C, int O>
__global__ __launch_bounds__(256) void k_gemm_ab(
    const float* __restrict__ XT, const float* __restrict__ WP,
    float* __restrict__ AB)
{
  constexpr int P = 16;
  constexpr int TWO = 2*O;
  constexpr int CO = (TWO + 255)/256;
  __shared__ __align__(16) float Xs[P][C];
  int tid = threadIdx.x;
  int sb = (blockIdx.x & 7)*64 + (blockIdx.x >> 3);    // batch = blockIdx%8
  long bn0 = (long)sb * P;
  for (int t = tid; t < P*C; t += 256) (&Xs[0][0])[t] = XT[bn0*C + t];
  __syncthreads();
  float acc[CO][P];
  #pragma unroll
  for (int j=0;j<CO;j++)
    #pragma unroll
    for (int r=0;r<P;r++) acc[j][r] = 0.f;
  for (int c4 = 0; c4 < C/4; ++c4){
    float4 w[CO];
    #pragma unroll
    for (int j=0;j<CO;j++){
      int o = tid + j*256;
      if (o < TWO) w[j] = *(const float4*)(WP + ((size_t)c4*TWO + o)*4);
    }
    #pragma unroll
    for (int r=0;r<P;r++){
      float4 xv = *(const float4*)(&Xs[r][c4*4]);
      #pragma unroll
      for (int j=0;j<CO;j++){
        acc[j][r] = fmaf(w[j].x, xv.x, acc[j][r]);
        acc[j][r] = fmaf(w[j].y, xv.y, acc[j][r]);
        acc[j][r] = fmaf(w[j].z, xv.z, acc[j][r]);
        acc[j][r] = fmaf(w[j].w, xv.w, acc[j][r]);
      }
    }
  }
  #pragma unroll
  for (int j=0;j<CO;j++){
    int o = tid + j*256;
    if (o < TWO)
      for (int r=0;r<P;r++) AB[(bn0 + r)*TWO + o] = acc[j][r];
  }
}

// ---------- gather-reduce: y = A[idx] + B[n]; max/sum/sumsq over k ----------
template<int O, int P>
__global__ __launch_bounds__(256) void k_egather(
    const float* __restrict__ AB, const int* __restrict__ IDX,
    float* __restrict__ YMT, u64* __restrict__ SP)
{
  constexpr int TWO = 2*O;
  constexpr int S = 256/O;
  constexpr int PS = P/S;
  __shared__ int is[P][KK];
  int tid = threadIdx.x;
  int sb = (blockIdx.x & 7)*64 + (blockIdx.x >> 3);    // batch = blockIdx%8
  long bn0 = (long)sb * P;
  long b10 = (bn0 >> 10) << 10;
  for (int t = tid; t < P*KK; t += 256) (&is[0][0])[t] = IDX[bn0*KK + t];
  __syncthreads();
  int strand = tid / O;
  int o = tid - strand*O;
  float s = 0.f, s2 = 0.f;
  #pragma unroll
  for (int ps = 0; ps < PS; ++ps){
    int p = strand*PS + ps;
    long bn = bn0 + p;
    float bv = AB[bn*TWO + O + o];
    float mx = -INFINITY;
    #pragma unroll
    for (int k = 0; k < KK; ++k){
      long row = b10 + is[p][k];
      float v = AB[row*TWO + o] + bv;
      mx = fmaxf(mx, v);
      s += v; s2 = fmaf(v,v,s2);
    }
    YMT[bn*O + o] = mx;
  }
  int ch = (sb * S + strand) & 63;
  statadd(SP, O, ch, o, s, s2);
}

// ---------- stats finalize: mean + invstd (fixed-order integer sum: exact) ----------
__global__ void k_bnfin(const u64* __restrict__ SP, float* __restrict__ MV, int O, float cnt)
{
  int o = blockIdx.x*blockDim.x + threadIdx.x;
  if (o >= O) return;
  long long S = 0, S2 = 0;
  for (int ch = 0; ch < 64; ++ch){
    S  += (long long)SP[(size_t)ch*2*O + o];
    S2 += (long long)SP[(size_t)ch*2*O + O + o];
  }
  double m = (double)S / ((double)FXSCALE * (double)cnt);
  double ms2 = (double)S2 / ((double)FXSCALE * (double)cnt);
  double var = ms2 - m*m;
  MV[o] = (float)m;
  MV[O + o] = (float)(1.0 / sqrt(var + (double)EPSBN));
}

// ---------- t-net conv2 (recompute conv1 in LDS), RO=2, b128 h1 reads ----------
__global__ __launch_bounds__(64) void k_tconv2(
    const float* __restrict__ XT, const int* __restrict__ IDX,
    const float* __restrict__ W1, const float* __restrict__ MV1,
    const float* __restrict__ W2T, float* __restrict__ M2T, u64* __restrict__ SP)
{
  __shared__ float nb[KK*3];
  __shared__ float ctr[3];
  __shared__ __align__(16) float h1t[64*KK];   // [o][k]
  __shared__ int is[KK];
  int tid = threadIdx.x;               // 64
  int bn = blockIdx.x;
  int b = bn >> 10;
  if (tid < KK) is[tid] = IDX[bn*KK + tid];
  __syncthreads();
  if (tid < 60){ int k = tid/3, c = tid - k*3; nb[tid] = XT[((long)(b<<10)+is[k])*3 + c]; }
  if (tid < 3) ctr[tid] = XT[(long)bn*3 + tid];
  __syncthreads();
  {
    const float* wp = W1 + tid*6;
    float w0=wp[0], w1=wp[1], w2=wp[2];
    float cterm = fmaf(wp[3]-w0, ctr[0], fmaf(wp[4]-w1, ctr[1], (wp[5]-w2)*ctr[2]));
    float m = MV1[tid], iv = MV1[64+tid];
    #pragma unroll
    for (int k=0;k<KK;k++){
      float y = cterm;
      y = fmaf(w0, nb[k*3],   y);
      y = fmaf(w1, nb[k*3+1], y);
      y = fmaf(w2, nb[k*3+2], y);
      h1t[tid*KK + k] = lrelu((y - m) * iv);
    }
  }
  __syncthreads();
  float acc[2][KK];
  #pragma unroll
  for (int j=0;j<2;j++)
    #pragma unroll
    for (int k=0;k<KK;k++) acc[j][k]=0.f;
  #pragma unroll 2
  for (int c=0;c<64;++c){
    float wv0 = W2T[c*128 + tid];
    float wv1 = W2T[c*128 + 64 + tid];
    const float4* hp = (const float4*)(h1t + c*KK);
    float hv[KK];
    #pragma unroll
    for (int q=0;q<5;q++){
      float4 v4 = hp[q];
      hv[q*4]=v4.x; hv[q*4+1]=v4.y; hv[q*4+2]=v4.z; hv[q*4+3]=v4.w;
    }
    #pragma unroll
    for (int k=0;k<KK;k++){
      acc[0][k] = fmaf(wv0, hv[k], acc[0][k]);
      acc[1][k] = fmaf(wv1, hv[k], acc[1][k]);
    }
  }
  int ch = bn & 63;
  #pragma unroll
  for (int j=0;j<2;j++){
    int o = tid + j*64;
    float mx=-INFINITY, s=0.f, s2=0.f;
    #pragma unroll
    for (int k=0;k<KK;k++){ float v = acc[j][k]; mx = fmaxf(mx, v); s += v; s2 = fmaf(v,v,s2); }
    M2T[(long)bn*128 + o] = mx;
    statadd(SP, 128, ch, o, s, s2);
  }
}

// ---------- BN+lrelu from [bn][O] -> [b][*][n] dst (+ optional XT/xx + bf16 XB row) ----------
__global__ __launch_bounds__(256) void k_apply_t(
    const float* __restrict__ SRC, const float* __restrict__ MV,
    int O, float* __restrict__ DST, long dbs, int choff,
    float* __restrict__ XTN, float* __restrict__ XXN,
    ushort_t* __restrict__ XB)
{
  int bn = blockIdx.x*256 + threadIdx.x;
  if (bn >= BN_*NN) return;
  int b = bn >> 10, n = bn & 1023;
  const float4* src = (const float4*)(SRC + (long)bn*O);
  float4* xo = XTN ? (float4*)(XTN + (long)bn*O) : nullptr;
  u64* xbw = XB ? (u64*)(XB + (size_t)bn*512 + choff) : nullptr;
  float ss = 0.f;
  for (int o4 = 0; o4 < O/4; ++o4){
    float4 v = src[o4];
    float vv[4] = {v.x, v.y, v.z, v.w};
    float rr[4];
    #pragma unroll
    for (int u=0;u<4;u++){
      int o = o4*4+u;
      float t = lrelu((vv[u] - MV[o]) * MV[O+o]);
      rr[u] = t;
      ss = fmaf(t,t,ss);
      DST[(long)b*dbs + (long)(choff+o)*NN + n] = t;
    }
    if (xo) xo[o4] = make_float4(rr[0],rr[1],rr[2],rr[3]);
    if (xbw){
      u64 pk = (u64)f2b(rr[0]) | ((u64)f2b(rr[1]) << 16)
             | ((u64)f2b(rr[2]) << 32) | ((u64)f2b(rr[3]) << 48);
      xbw[o4] = pk;
    }
  }
  if (XXN) XXN[bn] = ss;
}

// ---------- weight transpose [O][C] -> [C][O] ----------
__global__ void k_wprep_t(const float* __restrict__ W, float* __restrict__ WT, int O, int C)
{
  int g = blockIdx.x*256+threadIdx.x;
  if (g >= O*C) return;
  int o = g / C, c = g - o*C;
  WT[(long)c*O + o] = W[g];
}

// ---------- quad weight pack for k_gemm_sm: [1024][C] -> WQ[c][t][4] ----------
__global__ void k_wprep_q(const float* __restrict__ W, float* __restrict__ WQ, int C)
{
  int g = blockIdx.x*256+threadIdx.x;
  if (g >= 1024*C) return;
  int o = g / C, c = g - o*C;
  int j = o >> 8, t = o & 255;
  WQ[((size_t)c*256 + t)*4 + j] = W[g];
}

// ---------- MFMA B-operand pack: w6[1024][512] -> bf16 frags ----------
__global__ void k_wprep_mf(const float* __restrict__ W, ushort_t* __restrict__ WB)
{
  int g = blockIdx.x*256+threadIdx.x;
  if (g >= 1024*512) return;
  int o = g >> 9, c = g & 511;
  int ks = c >> 5, kk = c & 31;
  int l = (kk >> 3)*16 + (o & 15);
  int e = kk & 7;
  WB[(((size_t)(o >> 4)*16 + ks)*64 + l)*8 + e] = f2b(W[g]);
}

// ---------- edge weight prep: [O][2C] -> packed WP [C/4][2O][4] ----------
__global__ void k_wprep_e2(const float* __restrict__ W, float* __restrict__ WP, int O, int C)
{
  int g = blockIdx.x*256+threadIdx.x;
  if (g >= O*C) return;
  int o = g / C, c = g - o*C;
  float wf = W[(long)o*2*C + c];
  float wc = W[(long)o*2*C + C + c];
  size_t base = ((size_t)(c>>2)*(2*O))*4 + (c&3);
  WP[base + (size_t)o*4]       = wf;
  WP[base + (size_t)(O+o)*4]   = wc - wf;
}

// ---------- dense GEMM (R13 proven): RO=4, n-tile 16, scalar X, W depth-2 prefetch ----------
__global__ __launch_bounds__(256, 1) void k_gemm_sm(
    const float* __restrict__ WQ, const float* __restrict__ X,
    long bsX, int C, unsigned* __restrict__ MX, u64* __restrict__ SP)
{
  int tid = threadIdx.x;
  int bt = blockIdx.x;
  int b = bt >> 6;
  int n0 = (bt & 63) << 4;
  const float* xrow = X + (long)b*bsX + n0;
  float acc[4][16];
  #pragma unroll
  for (int j=0;j<4;j++)
    #pragma unroll
    for (int i=0;i<16;i++) acc[j][i]=0.f;
  const float4* wq = (const float4*)WQ;

  auto gemm_step = [&](int cc, float4 wv){
    const float4* xc = (const float4*)(xrow + (size_t)cc*NN);
    float4 xa = xc[0], xb2 = xc[1], xe = xc[2], xf = xc[3];
    float wj[4] = {wv.x, wv.y, wv.z, wv.w};
    #pragma unroll
    for (int j=0;j<4;j++){
      float ww = wj[j];
      acc[j][0]=fmaf(ww,xa.x,acc[j][0]);  acc[j][1]=fmaf(ww,xa.y,acc[j][1]);
      acc[j][2]=fmaf(ww,xa.z,acc[j][2]);  acc[j][3]=fmaf(ww,xa.w,acc[j][3]);
      acc[j][4]=fmaf(ww,xb2.x,acc[j][4]);  acc[j][5]=fmaf(ww,xb2.y,acc[j][5]);
      acc[j][6]=fmaf(ww,xb2.z,acc[j][6]);  acc[j][7]=fmaf(ww,xb2.w,acc[j][7]);
      acc[j][8]=fmaf(ww,xe.x,acc[j][8]);  acc[j][9]=fmaf(ww,xe.y,acc[j][9]);
      acc[j][10]=fmaf(ww,xe.z,acc[j][10]); acc[j][11]=fmaf(ww,xe.w,acc[j][11]);
      acc[j][12]=fmaf(ww,xf.x,acc[j][12]); acc[j][13]=fmaf(ww,xf.y,acc[j][13]);
      acc[j][14]=fmaf(ww,xf.z,acc[j][14]); acc[j][15]=fmaf(ww,xf.w,acc[j][15]);
    }
  };

  float4 w0 = wq[tid];
  float4 w1 = wq[256 + tid];
  for (int c = 0; c < C-2; c += 2){
    float4 p0 = wq[(size_t)(c+2)*256 + tid];
    float4 p1 = wq[(size_t)(c+3)*256 + tid];
    gemm_step(c,   w0);
    gemm_step(c+1, w1);
    w0 = p0; w1 = p1;
  }
  gemm_step(C-2, w0);
  gemm_step(C-1, w1);

  int ch = bt & 63;
  #pragma unroll
  for (int j=0;j<4;j++){
    int o = tid + j*256;
    float mx=-INFINITY, s=0.f, s2=0.f;
    #pragma unroll
    for (int i=0;i<16;i++){ float v=acc[j][i]; mx=fmaxf(mx,v); s+=v; s2=fmaf(v,v,s2); }
    atomicMax(&MX[(b<<10) + o], fmap(mx));
    statadd(SP, 1024, ch, o, s, s2);
  }
}

// ---------- MFMA bf16 GEMM for w6: y^T[n][o] tiles, fused max/stats ----------
__global__ __launch_bounds__(256) void k_gemm_mfma(
    const ushort_t* __restrict__ WB, const ushort_t* __restrict__ XB,
    unsigned* __restrict__ MX, u64* __restrict__ SP)
{
  int tid = threadIdx.x;
  int w = tid >> 6, lane = tid & 63;
  int b = blockIdx.x >> 4;
  int ob = blockIdx.x & 15;
  int otile = ob*4 + w;              // 0..63
  int o0 = otile << 4;
  short8v wfrag[16];
  const short8v* wp = (const short8v*)WB;
  #pragma unroll
  for (int ks=0; ks<16; ++ks)
    wfrag[ks] = wp[((size_t)otile*16 + ks)*64 + lane];

  float mx = -INFINITY, s = 0.f, s2 = 0.f;
  int nbase = blockIdx.y*256;
  for (int nt = 0; nt < 16; ++nt){
    int n0 = nbase + nt*16;
    const short8v* xp = (const short8v*)(XB + ((size_t)(b<<10) + n0 + (lane & 15))*512 + (lane >> 4)*8);
    f32x4 acc = {0.f, 0.f, 0.f, 0.f};
    #pragma unroll
    for (int ks=0; ks<16; ++ks){
      short8v a = xp[ks*4];
      acc = __builtin_amdgcn_mfma_f32_16x16x32_bf16(a, wfrag[ks], acc, 0, 0, 0);
    }
    #pragma unroll
    for (int reg=0; reg<4; ++reg){
      float v = acc[reg];
      mx = fmaxf(mx, v); s += v; s2 = fmaf(v, v, s2);
    }
  }
  #pragma unroll
  for (int off=16; off<=32; off<<=1){
    mx = fmaxf(mx, __shfl_xor(mx, off));
    s += __shfl_xor(s, off);
    s2 += __shfl_xor(s2, off);
  }
  if (lane < 16){
    int o = o0 + lane;
    atomicMax(&MX[(b<<10) + o], fmap(mx));
    int ch = ((blockIdx.x << 2) + w + (blockIdx.y << 4)) & 63;
    statadd(SP, 1024, ch, o, s, s2);
  }
}

// ---------- unmap max + BN + lrelu ----------
__global__ void k_finmax(const unsigned* __restrict__ MX, const float* __restrict__ MV,
                         float* __restrict__ OUT)
{
  int g = blockIdx.x*256+threadIdx.x;
  if (g >= BN_*1024) return;
  int o = g & 1023;
  OUT[g] = lrelu((funmap(MX[g]) - MV[o]) * MV[1024+o]);
}

// ---------- fused FC + batch-BN + lrelu: one wave per feature ----------
__global__ __launch_bounds__(256) void k_fcbn(
    const float* __restrict__ A, const float* __restrict__ W,
    const float* __restrict__ bias, int C, int F, float* __restrict__ Z)
{
  int wv = threadIdx.x >> 6, lane = threadIdx.x & 63;
  int f = blockIdx.x*4 + wv;
  if (f >= F) return;
  const float* w = W + (long)f*C;
  float acc[8];
  #pragma unroll
  for (int b=0;b<8;b++) acc[b]=0.f;
  for (int c = lane; c < C; c += 64){
    float wvv = w[c];
    #pragma unroll
    for (int b=0;b<8;b++) acc[b] = fmaf(wvv, A[b*C + c], acc[b]);
  }
  #pragma unroll
  for (int b=0;b<8;b++){
    #pragma unroll
    for (int off=32; off>0; off>>=1) acc[b] += __shfl_xor(acc[b], off);
  }
  float bs = bias ? bias[f] : 0.f;
  float m = 0.f;
  #pragma unroll
  for (int b=0;b<8;b++){ acc[b] += bs; m += acc[b]; }
  m *= 0.125f;
  float var = 0.f;
  #pragma unroll
  for (int b=0;b<8;b++){ float d = acc[b]-m; var = fmaf(d,d,var); }
  var *= 0.125f;
  float is = rsqrtf(var + EPSBN);
  if (lane < 8) Z[lane*F + f] = lrelu((acc[lane]-m)*is);
}

// ---------- fc3 + bias + eye -> T[8,9], one wave per output ----------
__global__ __launch_bounds__(256) void k_fc3w(
    const float* __restrict__ A, const float* __restrict__ W,
    const float* __restrict__ bias, float* __restrict__ T9)
{
  int g = blockIdx.x*4 + (threadIdx.x >> 6);
  int lane = threadIdx.x & 63;
  if (g >= 72) return;
  int b = g / 9, j = g - b*9;
  const float* a = A + b*256;
  const float* w = W + j*256;
  float s = 0.f;
  for (int c = lane; c < 256; c += 64) s = fmaf(a[c], w[c], s);
  #pragma unroll
  for (int off=32; off>0; off>>=1) s += __shfl_xor(s, off);
  if (lane == 0){
    s += bias[j];
    if (j==0 || j==4 || j==8) s += 1.f;
    T9[g] = s;
  }
}

// ---------- apply 3x3 transform: xtr = T @ x ----------
__global__ void k_tapply(const float* __restrict__ Xin, const float* __restrict__ T9,
                         float* __restrict__ Xtr)
{
  int g = blockIdx.x*256+threadIdx.x;
  if (g >= BN_*3*NN) return;
  int n = g & 1023;
  int i = (g >> 10) % 3;
  int b = g / (3*NN);
  const float* t = T9 + b*9 + i*3;
  const float* xb = Xin + (long)b*3*NN + n;
  Xtr[g] = fmaf(t[0], xb[0], fmaf(t[1], xb[NN], t[2]*xb[2*NN]));
}

extern "C" void kernel_launch(void* const* d_in, const int* in_sizes, int n_in,
                              void* d_out, int out_size, void* d_ws, size_t ws_size,
                              hipStream_t stream)
{
  (void)in_sizes; (void)n_in; (void)out_size;
  const float* x     = (const float*)d_in[0];
  const float* tw1   = (const float*)d_in[1];
  const float* tw2   = (const float*)d_in[2];
  const float* tw3   = (const float*)d_in[3];
  const float* tfc1w = (const float*)d_in[4];
  const float* tfc2w = (const float*)d_in[5];
  const float* tfc2b = (const float*)d_in[6];
  const float* tfc3w = (const float*)d_in[7];
  const float* tfc3b = (const float*)d_in[8];
  const float* w1    = (const float*)d_in[9];
  const float* w2    = (const float*)d_in[10];
  const float* w3    = (const float*)d_in[11];
  const float* w4    = (const float*)d_in[12];
  const float* w6    = (const float*)d_in[13];
  float* out = (float*)d_out;

  char* ws = (char*)d_ws;
  size_t off = 0;
  auto alloc = [&](size_t bytes) -> void* {
    off = (off + 255) & ~(size_t)255;
    void* p = ws + off;
    off += bytes;
    return p;
  };
  auto spb = [](int O){ return (size_t)64*2*O*8; };

  float*    xt   = (float*)alloc((size_t)BN_*NN*128*4);
  float*    xx   = (float*)alloc((size_t)BN_*NN*4);
  int*      idx  = (int*)  alloc((size_t)BN_*NN*KK*4);
  float*    ymt  = (float*)alloc((size_t)BN_*NN*256*4);   // also m2t
  float*    ab   = (float*)alloc((size_t)BN_*NN*512*4);
  float*    xcat = (float*)alloc((size_t)BN_*512*NN*4);
  float*    xtr  = (float*)alloc((size_t)BN_*3*NN*4);
  float*    m2   = (float*)alloc((size_t)BN_*128*NN*4);
  ushort_t* xb16 = (ushort_t*)alloc((size_t)BN_*NN*512*2);
  ushort_t* wb16 = (ushort_t*)alloc((size_t)1024*512*2);
  // --- zero-once region ---
  size_t zoff0 = (off + 255) & ~(size_t)255;
  u64*      sp_e1 = (u64*)alloc(spb(64));
  u64*      sp_tc = (u64*)alloc(spb(128));
  u64*      sp_g1 = (u64*)alloc(spb(1024));
  u64*      sp_L1 = (u64*)alloc(spb(64));
  u64*      sp_L2 = (u64*)alloc(spb(64));
  u64*      sp_L3 = (u64*)alloc(spb(128));
  u64*      sp_L4 = (u64*)alloc(spb(256));
  u64*      sp_g2 = (u64*)alloc(spb(1024));
  unsigned* mxu1  = (unsigned*)alloc((size_t)BN_*1024*4);
  unsigned* mxu2  = (unsigned*)alloc((size_t)BN_*1024*4);
  size_t ztotal = off - zoff0;
  // --- end zero-once region ---
  float*    mv1  = (float*)alloc(2*64*4);
  float*    mv2  = (float*)alloc(2*128*4);
  float*    mv3  = (float*)alloc(2*1024*4);
  float*    mvL  = (float*)alloc(2*256*4);
  float*    mv6  = (float*)alloc(2*1024*4);
  float*    vbuf = (float*)alloc((size_t)BN_*1024*4);
  float*    z1   = (float*)alloc((size_t)BN_*512*4);
  float*    z2   = (float*)alloc((size_t)BN_*256*4);
  float*    T9   = (float*)alloc(72*4);
  float*    wt3q = (float*)alloc((size_t)128*1024*4);
  float*    wt2t = (float*)alloc((size_t)64*128*4);
  float*    w2p  = (float*)alloc((size_t)64*128*4);
  float*    w3p  = (float*)alloc((size_t)64*256*4);
  float*    w4p  = (float*)alloc((size_t)128*512*4);
  if (off > ws_size) return;

  float* m2t = ymt;

  const float CNTK = 8.f*1024.f*20.f;
  const float CNTN = 8.f*1024.f;

  hipMemsetAsync((char*)ws + zoff0, 0, ztotal, stream);

  // ===== weight prep =====
  k_wprep_t<<<(128*64+255)/256, 256, 0, stream>>>(tw2, wt2t, 128, 64);
  k_wprep_q<<<(1024*128)/256, 256, 0, stream>>>(tw3, wt3q, 128);
  k_wprep_mf<<<(1024*512)/256, 256, 0, stream>>>(w6, wb16);
  k_wprep_e2<<<(64*64+255)/256, 256, 0, stream>>>(w2, w2p, 64, 64);
  k_wprep_e2<<<(128*64+255)/256, 256, 0, stream>>>(w3, w3p, 128, 64);
  k_wprep_e2<<<(256*128+255)/256, 256, 0, stream>>>(w4, w4p, 256, 128);

  // ===== transform net =====
  k_transq<<<32, 256, 0, stream>>>(x, 3L*NN, 3, xt, xx);
  k_knn<<<1024, 256, 8*3*4, stream>>>(x, 3L*NN, xt, xx, idx, 3);
  k_edgeconv3<<<BN_*NN, 64, 0, stream>>>(xt, idx, tw1, ymt, sp_e1);
  k_bnfin<<<1, 64, 0, stream>>>(sp_e1, mv1, 64, CNTK);
  k_tconv2<<<BN_*NN, 64, 0, stream>>>(xt, idx, tw1, mv1, wt2t, m2t, sp_tc);
  k_bnfin<<<2, 64, 0, stream>>>(sp_tc, mv2, 128, CNTK);
  k_apply_t<<<32, 256, 0, stream>>>(m2t, mv2, 128, m2, 128L*NN, 0, nullptr, nullptr, nullptr);
  k_gemm_sm<<<BN_*64, 256, 0, stream>>>(wt3q, m2, 128L*NN, 128, mxu1, sp_g1);
  k_bnfin<<<16, 64, 0, stream>>>(sp_g1, mv3, 1024, CNTN);
  k_finmax<<<32, 256, 0, stream>>>(mxu1, mv3, vbuf);
  k_fcbn<<<128, 256, 0, stream>>>(vbuf, tfc1w, nullptr, 1024, 512, z1);
  k_fcbn<<<64, 256, 0, stream>>>(z1, tfc2w, tfc2b, 512, 256, z2);
  k_fc3w<<<18, 256, 0, stream>>>(z2, tfc3w, tfc3b, T9);
  k_tapply<<<(BN_*3*NN)/256, 256, 0, stream>>>(x, T9, xtr);

  // ===== edge conv stack =====
  k_transq<<<32, 256, 0, stream>>>(xtr, 3L*NN, 3, xt, xx);
  k_knn<<<1024, 256, 8*3*4, stream>>>(xtr, 3L*NN, xt, xx, idx, 3);
  k_edgeconv3<<<BN_*NN, 64, 0, stream>>>(xt, idx, w1, ymt, sp_L1);
  k_bnfin<<<1, 64, 0, stream>>>(sp_L1, mvL, 64, CNTK);
  k_apply_t<<<32, 256, 0, stream>>>(ymt, mvL, 64, xcat, 512L*NN, 0, xt, xx, xb16);
  // L2
  k_knn<<<1024, 256, 8*64*4, stream>>>(xcat, 512L*NN, xt, xx, idx, 64);
  k_gemm_ab<64,64><<<512, 256, 0, stream>>>(xt, w2p, ab);
  k_egather<64,16><<<512, 256, 0, stream>>>(ab, idx, ymt, sp_L2);
  k_bnfin<<<1, 64, 0, stream>>>(sp_L2, mvL, 64, CNTK);
  k_apply_t<<<32, 256, 0, stream>>>(ymt, mvL, 64, xcat, 512L*NN, 64, xt, xx, xb16);
  // L3
  k_knn<<<1024, 256, 8*64*4, stream>>>(xcat + 64L*NN, 512L*NN, xt, xx, idx, 64);
  k_gemm_ab<64,128><<<512, 256, 0, stream>>>(xt, w3p, ab);
  k_egather<128,16><<<512, 256, 0, stream>>>(ab, idx, ymt, sp_L3);
  k_bnfin<<<2, 64, 0, stream>>>(sp_L3, mvL, 128, CNTK);
  k_apply_t<<<32, 256, 0, stream>>>(ymt, mvL, 128, xcat, 512L*NN, 128, xt, xx, xb16);
  // L4
  k_knn<<<1024, 256, 8*128*4, stream>>>(xcat + 128L*NN, 512L*NN, xt, xx, idx, 128);
  k_gemm_ab<128,256><<<512, 256, 0, stream>>>(xt, w4p, ab);
  k_egather<256,16><<<512, 256, 0, stream>>>(ab, idx, ymt, sp_L4);
  k_bnfin<<<4, 64, 0, stream>>>(sp_L4, mvL, 256, CNTK);
  k_apply_t<<<32, 256, 0, stream>>>(ymt, mvL, 256, xcat, 512L*NN, 256, nullptr, nullptr, xb16);

  // ===== final conv w6 via MFMA bf16 + BN + lrelu + max over N =====
  k_gemm_mfma<<<dim3(BN_*16, 4), 256, 0, stream>>>(wb16, xb16, mxu2, sp_g2);
  k_bnfin<<<16, 64, 0, stream>>>(sp_g2, mv6, 1024, CNTN);
  k_finmax<<<32, 256, 0, stream>>>(mxu2, mv6, out);
}

// Round 22
// 782.615 us; speedup vs baseline: 1.3931x; 1.0008x over previous
//
#include <hip/hip_runtime.h>
#include <math.h>

#define BN_ 8
#define NN 1024
#define KK 20
#define EPSBN 1e-5f
#define FXSCALE 1048576.0f   // 2^20 fixed-point scale for deterministic stats

typedef unsigned long long u64;
typedef unsigned short ushort_t;
typedef __attribute__((ext_vector_type(8))) short short8v;   // 8 bf16 (4 VGPRs)
typedef __attribute__((ext_vector_type(4))) float f32x4;     // MFMA acc

__device__ __forceinline__ float lrelu(float x){ return x > 0.f ? x : 0.2f*x; }

__device__ __forceinline__ unsigned fmap(float x){
  unsigned u = __float_as_uint(x);
  return (u & 0x80000000u) ? ~u : (u | 0x80000000u);
}
__device__ __forceinline__ float funmap(unsigned m){
  unsigned u = (m & 0x80000000u) ? (m & 0x7FFFFFFFu) : ~m;
  return __uint_as_float(u);
}
__device__ __forceinline__ ushort_t f2b(float f){   // RNE fp32 -> bf16 bits
  unsigned u = __float_as_uint(f);
  unsigned r = (u + 0x7FFFu + ((u >> 16) & 1u)) >> 16;
  return (ushort_t)r;
}

__device__ __forceinline__ int mbcnt64(u64 m){
  return __builtin_amdgcn_mbcnt_hi((unsigned)(m >> 32),
         __builtin_amdgcn_mbcnt_lo((unsigned)m, 0));
}

__device__ __forceinline__ void statadd(u64* SP, int O, int ch, int o, float s, float s2){
  atomicAdd(&SP[(size_t)ch*2*O + o],     (u64)(long long)llrintf(s  * FXSCALE));
  atomicAdd(&SP[(size_t)ch*2*O + O + o], (u64)(long long)llrintf(s2 * FXSCALE));
}

// ---------- transpose [B,C,N]->[B,N,C] + per-point sum of squares (C=3 paths) ----------
__global__ void k_transq(const float* __restrict__ src, long bs, int C,
                         float* __restrict__ xt, float* __restrict__ xx)
{
  int g = blockIdx.x*256 + threadIdx.x;
  if (g >= BN_*NN) return;
  int b = g >> 10, n = g & 1023;
  const float* s = src + (long)b*bs + n;
  float* d = xt + (long)g*C;
  float ss = 0.f;
  for (int c = 0; c < C; ++c){ float v = s[(long)c*NN]; d[c] = v; ss += v*v; }
  xx[g] = ss;
}

// ---------- fused pairwise-dist (float4 loads) + top-20 radix-select (early-exit) ----------
__global__ __launch_bounds__(256) void k_knn(
    const float* __restrict__ X, long bsX,
    const float* __restrict__ XT, const float* __restrict__ XX,
    int* __restrict__ IDX, int C)
{
  extern __shared__ float sm[];          // xi for block's 8 rows: [8*C]
  int tid = threadIdx.x;
  int wave = tid >> 6, lane = tid & 63;
  int sb = (blockIdx.x & 7)*128 + (blockIdx.x >> 3);   // bijective, batch = blockIdx%8
  int b = sb >> 7;
  int i0 = (sb & 127) << 3;
  for (int t = tid; t < 8*C; t += 256){
    int rr = t / C, cc = t - rr*C;
    sm[t] = XT[((long)(b<<10) + i0 + rr)*C + cc];
  }
  __syncthreads();
  const float* xb = X + (long)b*bsX;
  float acc[2][16];
  #pragma unroll
  for (int r=0;r<2;r++)
    #pragma unroll
    for (int q=0;q<16;q++) acc[r][q]=0.f;
  const float* xi = sm + (wave*2)*C;
  for (int c = 0; c < C; ++c){
    const float4* xr4 = (const float4*)(xb + (long)c*NN);
    float4 xv4[4];
    #pragma unroll
    for (int q4=0;q4<4;q4++) xv4[q4] = xr4[q4*64 + lane];
    #pragma unroll
    for (int r=0;r<2;r++){
      float xiv = xi[r*C + c];
      #pragma unroll
      for (int q4=0;q4<4;q4++){
        acc[r][q4*4+0] = fmaf(xiv, xv4[q4].x, acc[r][q4*4+0]);
        acc[r][q4*4+1] = fmaf(xiv, xv4[q4].y, acc[r][q4*4+1]);
        acc[r][q4*4+2] = fmaf(xiv, xv4[q4].z, acc[r][q4*4+2]);
        acc[r][q4*4+3] = fmaf(xiv, xv4[q4].w, acc[r][q4*4+3]);
      }
    }
  }
  const float4* xx4 = (const float4*)(XX + (b<<10));
  float xxj[16];
  #pragma unroll
  for (int q4=0;q4<4;q4++){
    float4 t = xx4[q4*64 + lane];
    xxj[q4*4+0]=t.x; xxj[q4*4+1]=t.y; xxj[q4*4+2]=t.z; xxj[q4*4+3]=t.w;
  }
  const float* xxb = XX + (b<<10);
  int row0 = i0 + wave*2;
  #pragma unroll
  for (int r=0;r<2;r++){
    float xxi = xxb[row0 + r];
    #pragma unroll
    for (int q=0;q<16;q++) acc[r][q] = 2.f*acc[r][q] - xxi - xxj[q];
  }

  for (int r=0;r<2;r++){
    unsigned u[16];
    #pragma unroll
    for (int q=0;q<16;q++) u[q] = fmap(acc[r][q]);
    unsigned P = 0;
    for (int bit = 31; bit >= 0; --bit){
      unsigned cand = P | (1u << bit);
      int c = 0;
      #pragma unroll
      for (int q=0;q<16;q++) c += (int)__popcll(__ballot(u[q] >= cand));
      if (c >= KK){
        P = cand;
        if (c == KK) break;        // wave-uniform scalar branch
      }
    }
    int nG = 0;
    #pragma unroll
    for (int q=0;q<16;q++) nG += (int)__popcll(__ballot(u[q] > P));
    int navail = KK - nG;
    int slot = 0;
    int outb = ((b<<10) + row0 + r)*KK;
    #pragma unroll
    for (int q=0;q<16;q++){
      u64 mg = __ballot(u[q] > P);
      u64 me = __ballot(u[q] == P);
      int cg = (int)__popcll(mg);
      int ce = (int)__popcll(me);
      int take_e = navail < ce ? navail : ce;
      int nval = ((q >> 2) << 8) + (lane << 2) + (q & 3);
      if (u[q] > P){
        IDX[outb + slot + mbcnt64(mg)] = nval;
      } else if (u[q] == P){
        int rk = mbcnt64(me);
        if (rk < take_e) IDX[outb + slot + cg + rk] = nval;
      }
      slot += cg + take_e;
      navail -= take_e;
    }
  }
}

// ---------- old-style edge-conv for C=3 layers: writes coalesced YMT[bn][o] ----------
__global__ void k_edgeconv3(const float* __restrict__ XT, const int* __restrict__ IDX,
                            const float* __restrict__ W, float* __restrict__ YMT,
                            u64* __restrict__ SP)
{
  __shared__ float nb[KK*3];
  __shared__ float ctr[3];
  __shared__ int is[KK];
  const int C = 3, O = 64;
  int tid = threadIdx.x;
  int bn = blockIdx.x;
  int b = bn >> 10;
  if (tid < KK) is[tid] = IDX[bn*KK + tid];
  __syncthreads();
  if (tid < 60){ int k = tid/3, c = tid - k*3; nb[tid] = XT[((long)(b<<10)+is[k])*C + c]; }
  if (tid < 3) ctr[tid] = XT[(long)bn*C + tid];
  __syncthreads();
  int o = tid;
  const float* wp = W + (long)o*2*C;
  float yc = 0.f;
  #pragma unroll
  for (int c = 0; c < 3; ++c) yc = fmaf(wp[C+c] - wp[c], ctr[c], yc);
  float acc[KK];
  #pragma unroll
  for (int k=0;k<KK;k++) acc[k] = yc;
  #pragma unroll
  for (int c = 0; c < 3; ++c){
    float wf = wp[c];
    #pragma unroll
    for (int k=0;k<KK;k++) acc[k] = fmaf(wf, nb[k*3+c], acc[k]);
  }
  float mx = -INFINITY, s = 0.f, s2 = 0.f;
  #pragma unroll
  for (int k=0;k<KK;k++){ float v = acc[k]; mx = fmaxf(mx, v); s += v; s2 = fmaf(v,v,s2); }
  YMT[(long)bn*O + o] = mx;
  statadd(SP, O, bn & 63, o, s, s2);
}

// ---------- dense per-point GEMM: AB[bn][2O] = [Wf@x ; (Wc-Wf)@x] ----------
template<int C, int O>
__global__ __launch_bounds__(256) void k_gemm_ab(
    const float* __restrict__ XT, const float* __restrict__ WP,
    float* __restrict__ AB)
{
  constexpr int P = 16;
  constexpr int TWO = 2*O;
  constexpr int CO = (TWO + 255)/256;
  __shared__ __align__(16) float Xs[P][C];
  int tid = threadIdx.x;
  int sb = (blockIdx.x & 7)*64 + (blockIdx.x >> 3);    // batch = blockIdx%8
  long bn0 = (long)sb * P;
  for (int t = tid; t < P*C; t += 256) (&Xs[0][0])[t] = XT[bn0*C + t];
  __syncthreads();
  float acc[CO][P];
  #pragma unroll
  for (int j=0;j<CO;j++)
    #pragma unroll
    for (int r=0;r<P;r++) acc[j][r] = 0.f;
  for (int c4 = 0; c4 < C/4; ++c4){
    float4 w[CO];
    #pragma unroll
    for (int j=0;j<CO;j++){
      int o = tid + j*256;
      if (o < TWO) w[j] = *(const float4*)(WP + ((size_t)c4*TWO + o)*4);
    }
    #pragma unroll
    for (int r=0;r<P;r++){
      float4 xv = *(const float4*)(&Xs[r][c4*4]);
      #pragma unroll
      for (int j=0;j<CO;j++){
        acc[j][r] = fmaf(w[j].x, xv.x, acc[j][r]);
        acc[j][r] = fmaf(w[j].y, xv.y, acc[j][r]);
        acc[j][r] = fmaf(w[j].z, xv.z, acc[j][r]);
        acc[j][r] = fmaf(w[j].w, xv.w, acc[j][r]);
      }
    }
  }
  #pragma unroll
  for (int j=0;j<CO;j++){
    int o = tid + j*256;
    if (o < TWO)
      for (int r=0;r<P;r++) AB[(bn0 + r)*TWO + o] = acc[j][r];
  }
}

// ---------- gather-reduce: y = A[idx] + B[n]; max/sum/sumsq over k ----------
template<int O, int P>
__global__ __launch_bounds__(256) void k_egather(
    const float* __restrict__ AB, const int* __restrict__ IDX,
    float* __restrict__ YMT, u64* __restrict__ SP)
{
  constexpr int TWO = 2*O;
  constexpr int S = 256/O;
  constexpr int PS = P/S;
  __shared__ int is[P][KK];
  int tid = threadIdx.x;
  int sb = (blockIdx.x & 7)*64 + (blockIdx.x >> 3);    // batch = blockIdx%8
  long bn0 = (long)sb * P;
  long b10 = (bn0 >> 10) << 10;
  for (int t = tid; t < P*KK; t += 256) (&is[0][0])[t] = IDX[bn0*KK + t];
  __syncthreads();
  int strand = tid / O;
  int o = tid - strand*O;
  float s = 0.f, s2 = 0.f;
  #pragma unroll
  for (int ps = 0; ps < PS; ++ps){
    int p = strand*PS + ps;
    long bn = bn0 + p;
    float bv = AB[bn*TWO + O + o];
    float mx = -INFINITY;
    #pragma unroll
    for (int k = 0; k < KK; ++k){
      long row = b10 + is[p][k];
      float v = AB[row*TWO + o] + bv;
      mx = fmaxf(mx, v);
      s += v; s2 = fmaf(v,v,s2);
    }
    YMT[bn*O + o] = mx;
  }
  int ch = (sb * S + strand) & 63;
  statadd(SP, O, ch, o, s, s2);
}

// ---------- stats finalize: mean + invstd (fixed-order integer sum: exact) ----------
__global__ void k_bnfin(const u64* __restrict__ SP, float* __restrict__ MV, int O, float cnt)
{
  int o = blockIdx.x*blockDim.x + threadIdx.x;
  if (o >= O) return;
  long long S = 0, S2 = 0;
  for (int ch = 0; ch < 64; ++ch){
    S  += (long long)SP[(size_t)ch*2*O + o];
    S2 += (long long)SP[(size_t)ch*2*O + O + o];
  }
  double m = (double)S / ((double)FXSCALE * (double)cnt);
  double ms2 = (double)S2 / ((double)FXSCALE * (double)cnt);
  double var = ms2 - m*m;
  MV[o] = (float)m;
  MV[O + o] = (float)(1.0 / sqrt(var + (double)EPSBN));
}

// ---------- t-net conv2 (recompute conv1 in LDS), RO=2, b128 h1 reads ----------
__global__ __launch_bounds__(64) void k_tconv2(
    const float* __restrict__ XT, const int* __restrict__ IDX,
    const float* __restrict__ W1, const float* __restrict__ MV1,
    const float* __restrict__ W2T, float* __restrict__ M2T, u64* __restrict__ SP)
{
  __shared__ float nb[KK*3];
  __shared__ float ctr[3];
  __shared__ __align__(16) float h1t[64*KK];   // [o][k]
  __shared__ int is[KK];
  int tid = threadIdx.x;               // 64
  int bn = blockIdx.x;
  int b = bn >> 10;
  if (tid < KK) is[tid] = IDX[bn*KK + tid];
  __syncthreads();
  if (tid < 60){ int k = tid/3, c = tid - k*3; nb[tid] = XT[((long)(b<<10)+is[k])*3 + c]; }
  if (tid < 3) ctr[tid] = XT[(long)bn*3 + tid];
  __syncthreads();
  {
    const float* wp = W1 + tid*6;
    float w0=wp[0], w1=wp[1], w2=wp[2];
    float cterm = fmaf(wp[3]-w0, ctr[0], fmaf(wp[4]-w1, ctr[1], (wp[5]-w2)*ctr[2]));
    float m = MV1[tid], iv = MV1[64+tid];
    #pragma unroll
    for (int k=0;k<KK;k++){
      float y = cterm;
      y = fmaf(w0, nb[k*3],   y);
      y = fmaf(w1, nb[k*3+1], y);
      y = fmaf(w2, nb[k*3+2], y);
      h1t[tid*KK + k] = lrelu((y - m) * iv);
    }
  }
  __syncthreads();
  float acc[2][KK];
  #pragma unroll
  for (int j=0;j<2;j++)
    #pragma unroll
    for (int k=0;k<KK;k++) acc[j][k]=0.f;
  #pragma unroll 2
  for (int c=0;c<64;++c){
    float wv0 = W2T[c*128 + tid];
    float wv1 = W2T[c*128 + 64 + tid];
    const float4* hp = (const float4*)(h1t + c*KK);
    float hv[KK];
    #pragma unroll
    for (int q=0;q<5;q++){
      float4 v4 = hp[q];
      hv[q*4]=v4.x; hv[q*4+1]=v4.y; hv[q*4+2]=v4.z; hv[q*4+3]=v4.w;
    }
    #pragma unroll
    for (int k=0;k<KK;k++){
      acc[0][k] = fmaf(wv0, hv[k], acc[0][k]);
      acc[1][k] = fmaf(wv1, hv[k], acc[1][k]);
    }
  }
  int ch = bn & 63;
  #pragma unroll
  for (int j=0;j<2;j++){
    int o = tid + j*64;
    float mx=-INFINITY, s=0.f, s2=0.f;
    #pragma unroll
    for (int k=0;k<KK;k++){ float v = acc[j][k]; mx = fmaxf(mx, v); s += v; s2 = fmaf(v,v,s2); }
    M2T[(long)bn*128 + o] = mx;
    statadd(SP, 128, ch, o, s, s2);
  }
}

// ---------- BN+lrelu from [bn][O] -> [b][*][n] dst (+ optional XT/xx + bf16 XB row) ----------
__global__ __launch_bounds__(256) void k_apply_t(
    const float* __restrict__ SRC, const float* __restrict__ MV,
    int O, float* __restrict__ DST, long dbs, int choff,
    float* __restrict__ XTN, float* __restrict__ XXN,
    ushort_t* __restrict__ XB)
{
  int bn = blockIdx.x*256 + threadIdx.x;
  if (bn >= BN_*NN) return;
  int b = bn >> 10, n = bn & 1023;
  const float4* src = (const float4*)(SRC + (long)bn*O);
  float4* xo = XTN ? (float4*)(XTN + (long)bn*O) : nullptr;
  u64* xbw = XB ? (u64*)(XB + (size_t)bn*512 + choff) : nullptr;
  float ss = 0.f;
  for (int o4 = 0; o4 < O/4; ++o4){
    float4 v = src[o4];
    float vv[4] = {v.x, v.y, v.z, v.w};
    float rr[4];
    #pragma unroll
    for (int u=0;u<4;u++){
      int o = o4*4+u;
      float t = lrelu((vv[u] - MV[o]) * MV[O+o]);
      rr[u] = t;
      ss = fmaf(t,t,ss);
      DST[(long)b*dbs + (long)(choff+o)*NN + n] = t;
    }
    if (xo) xo[o4] = make_float4(rr[0],rr[1],rr[2],rr[3]);
    if (xbw){
      u64 pk = (u64)f2b(rr[0]) | ((u64)f2b(rr[1]) << 16)
             | ((u64)f2b(rr[2]) << 32) | ((u64)f2b(rr[3]) << 48);
      xbw[o4] = pk;
    }
  }
  if (XXN) XXN[bn] = ss;
}

// ---------- weight transpose [O][C] -> [C][O] ----------
__global__ void k_wprep_t(const float* __restrict__ W, float* __restrict__ WT, int O, int C)
{
  int g = blockIdx.x*256+threadIdx.x;
  if (g >= O*C) return;
  int o = g / C, c = g - o*C;
  WT[(long)c*O + o] = W[g];
}

// ---------- quad weight pack for k_gemm_sm: [1024][C] -> WQ[c][t][4] ----------
__global__ void k_wprep_q(const float* __restrict__ W, float* __restrict__ WQ, int C)
{
  int g = blockIdx.x*256+threadIdx.x;
  if (g >= 1024*C) return;
  int o = g / C, c = g - o*C;
  int j = o >> 8, t = o & 255;
  WQ[((size_t)c*256 + t)*4 + j] = W[g];
}

// ---------- MFMA B-operand pack: w6[1024][512] -> bf16 frags ----------
__global__ void k_wprep_mf(const float* __restrict__ W, ushort_t* __restrict__ WB)
{
  int g = blockIdx.x*256+threadIdx.x;
  if (g >= 1024*512) return;
  int o = g >> 9, c = g & 511;
  int ks = c >> 5, kk = c & 31;
  int l = (kk >> 3)*16 + (o & 15);
  int e = kk & 7;
  WB[(((size_t)(o >> 4)*16 + ks)*64 + l)*8 + e] = f2b(W[g]);
}

// ---------- edge weight prep: [O][2C] -> packed WP [C/4][2O][4] ----------
__global__ void k_wprep_e2(const float* __restrict__ W, float* __restrict__ WP, int O, int C)
{
  int g = blockIdx.x*256+threadIdx.x;
  if (g >= O*C) return;
  int o = g / C, c = g - o*C;
  float wf = W[(long)o*2*C + c];
  float wc = W[(long)o*2*C + C + c];
  size_t base = ((size_t)(c>>2)*(2*O))*4 + (c&3);
  WP[base + (size_t)o*4]       = wf;
  WP[base + (size_t)(O+o)*4]   = wc - wf;
}

// ---------- dense GEMM (R13 proven): RO=4, n-tile 16, scalar X, W depth-2 prefetch ----------
__global__ __launch_bounds__(256, 1) void k_gemm_sm(
    const float* __restrict__ WQ, const float* __restrict__ X,
    long bsX, int C, unsigned* __restrict__ MX, u64* __restrict__ SP)
{
  int tid = threadIdx.x;
  int bt = blockIdx.x;
  int b = bt >> 6;
  int n0 = (bt & 63) << 4;
  const float* xrow = X + (long)b*bsX + n0;
  float acc[4][16];
  #pragma unroll
  for (int j=0;j<4;j++)
    #pragma unroll
    for (int i=0;i<16;i++) acc[j][i]=0.f;
  const float4* wq = (const float4*)WQ;

  auto gemm_step = [&](int cc, float4 wv){
    const float4* xc = (const float4*)(xrow + (size_t)cc*NN);
    float4 xa = xc[0], xb2 = xc[1], xe = xc[2], xf = xc[3];
    float wj[4] = {wv.x, wv.y, wv.z, wv.w};
    #pragma unroll
    for (int j=0;j<4;j++){
      float ww = wj[j];
      acc[j][0]=fmaf(ww,xa.x,acc[j][0]);  acc[j][1]=fmaf(ww,xa.y,acc[j][1]);
      acc[j][2]=fmaf(ww,xa.z,acc[j][2]);  acc[j][3]=fmaf(ww,xa.w,acc[j][3]);
      acc[j][4]=fmaf(ww,xb2.x,acc[j][4]);  acc[j][5]=fmaf(ww,xb2.y,acc[j][5]);
      acc[j][6]=fmaf(ww,xb2.z,acc[j][6]);  acc[j][7]=fmaf(ww,xb2.w,acc[j][7]);
      acc[j][8]=fmaf(ww,xe.x,acc[j][8]);  acc[j][9]=fmaf(ww,xe.y,acc[j][9]);
      acc[j][10]=fmaf(ww,xe.z,acc[j][10]); acc[j][11]=fmaf(ww,xe.w,acc[j][11]);
      acc[j][12]=fmaf(ww,xf.x,acc[j][12]); acc[j][13]=fmaf(ww,xf.y,acc[j][13]);
      acc[j][14]=fmaf(ww,xf.z,acc[j][14]); acc[j][15]=fmaf(ww,xf.w,acc[j][15]);
    }
  };

  float4 w0 = wq[tid];
  float4 w1 = wq[256 + tid];
  for (int c = 0; c < C-2; c += 2){
    float4 p0 = wq[(size_t)(c+2)*256 + tid];
    float4 p1 = wq[(size_t)(c+3)*256 + tid];
    gemm_step(c,   w0);
    gemm_step(c+1, w1);
    w0 = p0; w1 = p1;
  }
  gemm_step(C-2, w0);
  gemm_step(C-1, w1);

  int ch = bt & 63;
  #pragma unroll
  for (int j=0;j<4;j++){
    int o = tid + j*256;
    float mx=-INFINITY, s=0.f, s2=0.f;
    #pragma unroll
    for (int i=0;i<16;i++){ float v=acc[j][i]; mx=fmaxf(mx,v); s+=v; s2=fmaf(v,v,s2); }
    atomicMax(&MX[(b<<10) + o], fmap(mx));
    statadd(SP, 1024, ch, o, s, s2);
  }
}

// ---------- MFMA bf16 GEMM for w6: y^T[n][o] tiles, fused max/stats ----------
__global__ __launch_bounds__(256) void k_gemm_mfma(
    const ushort_t* __restrict__ WB, const ushort_t* __restrict__ XB,
    unsigned* __restrict__ MX, u64* __restrict__ SP)
{
  int tid = threadIdx.x;
  int w = tid >> 6, lane = tid & 63;
  int b = blockIdx.x >> 4;
  int ob = blockIdx.x & 15;
  int otile = ob*4 + w;              // 0..63
  int o0 = otile << 4;
  short8v wfrag[16];
  const short8v* wp = (const short8v*)WB;
  #pragma unroll
  for (int ks=0; ks<16; ++ks)
    wfrag[ks] = wp[((size_t)otile*16 + ks)*64 + lane];

  float mx = -INFINITY, s = 0.f, s2 = 0.f;
  int nbase = blockIdx.y*256;
  for (int nt = 0; nt < 16; ++nt){
    int n0 = nbase + nt*16;
    const short8v* xp = (const short8v*)(XB + ((size_t)(b<<10) + n0 + (lane & 15))*512 + (lane >> 4)*8);
    f32x4 acc = {0.f, 0.f, 0.f, 0.f};
    #pragma unroll
    for (int ks=0; ks<16; ++ks){
      short8v a = xp[ks*4];
      acc = __builtin_amdgcn_mfma_f32_16x16x32_bf16(a, wfrag[ks], acc, 0, 0, 0);
    }
    #pragma unroll
    for (int reg=0; reg<4; ++reg){
      float v = acc[reg];
      mx = fmaxf(mx, v); s += v; s2 = fmaf(v, v, s2);
    }
  }
  #pragma unroll
  for (int off=16; off<=32; off<<=1){
    mx = fmaxf(mx, __shfl_xor(mx, off));
    s += __shfl_xor(s, off);
    s2 += __shfl_xor(s2, off);
  }
  if (lane < 16){
    int o = o0 + lane;
    atomicMax(&MX[(b<<10) + o], fmap(mx));
    int ch = ((blockIdx.x << 2) + w + (blockIdx.y << 4)) & 63;
    statadd(SP, 1024, ch, o, s, s2);
  }
}

// ---------- unmap max + BN + lrelu ----------
__global__ void k_finmax(const unsigned* __restrict__ MX, const float* __restrict__ MV,
                         float* __restrict__ OUT)
{
  int g = blockIdx.x*256+threadIdx.x;
  if (g >= BN_*1024) return;
  int o = g & 1023;
  OUT[g] = lrelu((funmap(MX[g]) - MV[o]) * MV[1024+o]);
}

// ---------- fused FC + batch-BN + lrelu: one wave per feature ----------
__global__ __launch_bounds__(256) void k_fcbn(
    const float* __restrict__ A, const float* __restrict__ W,
    const float* __restrict__ bias, int C, int F, float* __restrict__ Z)
{
  int wv = threadIdx.x >> 6, lane = threadIdx.x & 63;
  int f = blockIdx.x*4 + wv;
  if (f >= F) return;
  const float* w = W + (long)f*C;
  float acc[8];
  #pragma unroll
  for (int b=0;b<8;b++) acc[b]=0.f;
  for (int c = lane; c < C; c += 64){
    float wvv = w[c];
    #pragma unroll
    for (int b=0;b<8;b++) acc[b] = fmaf(wvv, A[b*C + c], acc[b]);
  }
  #pragma unroll
  for (int b=0;b<8;b++){
    #pragma unroll
    for (int off=32; off>0; off>>=1) acc[b] += __shfl_xor(acc[b], off);
  }
  float bs = bias ? bias[f] : 0.f;
  float m = 0.f;
  #pragma unroll
  for (int b=0;b<8;b++){ acc[b] += bs; m += acc[b]; }
  m *= 0.125f;
  float var = 0.f;
  #pragma unroll
  for (int b=0;b<8;b++){ float d = acc[b]-m; var = fmaf(d,d,var); }
  var *= 0.125f;
  float is = rsqrtf(var + EPSBN);
  if (lane < 8) Z[lane*F + f] = lrelu((acc[lane]-m)*is);
}

// ---------- fc3 + bias + eye -> T[8,9], one wave per output ----------
__global__ __launch_bounds__(256) void k_fc3w(
    const float* __restrict__ A, const float* __restrict__ W,
    const float* __restrict__ bias, float* __restrict__ T9)
{
  int g = blockIdx.x*4 + (threadIdx.x >> 6);
  int lane = threadIdx.x & 63;
  if (g >= 72) return;
  int b = g / 9, j = g - b*9;
  const float* a = A + b*256;
  const float* w = W + j*256;
  float s = 0.f;
  for (int c = lane; c < 256; c += 64) s = fmaf(a[c], w[c], s);
  #pragma unroll
  for (int off=32; off>0; off>>=1) s += __shfl_xor(s, off);
  if (lane == 0){
    s += bias[j];
    if (j==0 || j==4 || j==8) s += 1.f;
    T9[g] = s;
  }
}

// ---------- apply 3x3 transform: xtr = T @ x ----------
__global__ void k_tapply(const float* __restrict__ Xin, const float* __restrict__ T9,
                         float* __restrict__ Xtr)
{
  int g = blockIdx.x*256+threadIdx.x;
  if (g >= BN_*3*NN) return;
  int n = g & 1023;
  int i = (g >> 10) % 3;
  int b = g / (3*NN);
  const float* t = T9 + b*9 + i*3;
  const float* xb = Xin + (long)b*3*NN + n;
  Xtr[g] = fmaf(t[0], xb[0], fmaf(t[1], xb[NN], t[2]*xb[2*NN]));
}

extern "C" void kernel_launch(void* const* d_in, const int* in_sizes, int n_in,
                              void* d_out, int out_size, void* d_ws, size_t ws_size,
                              hipStream_t stream)
{
  (void)in_sizes; (void)n_in; (void)out_size;
  const float* x     = (const float*)d_in[0];
  const float* tw1   = (const float*)d_in[1];
  const float* tw2   = (const float*)d_in[2];
  const float* tw3   = (const float*)d_in[3];
  const float* tfc1w = (const float*)d_in[4];
  const float* tfc2w = (const float*)d_in[5];
  const float* tfc2b = (const float*)d_in[6];
  const float* tfc3w = (const float*)d_in[7];
  const float* tfc3b = (const float*)d_in[8];
  const float* w1    = (const float*)d_in[9];
  const float* w2    = (const float*)d_in[10];
  const float* w3    = (const float*)d_in[11];
  const float* w4    = (const float*)d_in[12];
  const float* w6    = (const float*)d_in[13];
  float* out = (float*)d_out;

  char* ws = (char*)d_ws;
  size_t off = 0;
  auto alloc = [&](size_t bytes) -> void* {
    off = (off + 255) & ~(size_t)255;
    void* p = ws + off;
    off += bytes;
    return p;
  };
  auto spb = [](int O){ return (size_t)64*2*O*8; };

  float*    xt   = (float*)alloc((size_t)BN_*NN*128*4);
  float*    xx   = (float*)alloc((size_t)BN_*NN*4);
  int*      idx  = (int*)  alloc((size_t)BN_*NN*KK*4);
  float*    ymt  = (float*)alloc((size_t)BN_*NN*256*4);   // also m2t
  float*    ab   = (float*)alloc((size_t)BN_*NN*512*4);
  float*    xcat = (float*)alloc((size_t)BN_*512*NN*4);
  float*    xtr  = (float*)alloc((size_t)BN_*3*NN*4);
  float*    m2   = (float*)alloc((size_t)BN_*128*NN*4);
  ushort_t* xb16 = (ushort_t*)alloc((size_t)BN_*NN*512*2);
  ushort_t* wb16 = (ushort_t*)alloc((size_t)1024*512*2);
  // --- zero-once region ---
  size_t zoff0 = (off + 255) & ~(size_t)255;
  u64*      sp_e1 = (u64*)alloc(spb(64));
  u64*      sp_tc = (u64*)alloc(spb(128));
  u64*      sp_g1 = (u64*)alloc(spb(1024));
  u64*      sp_L1 = (u64*)alloc(spb(64));
  u64*      sp_L2 = (u64*)alloc(spb(64));
  u64*      sp_L3 = (u64*)alloc(spb(128));
  u64*      sp_L4 = (u64*)alloc(spb(256));
  u64*      sp_g2 = (u64*)alloc(spb(1024));
  unsigned* mxu1  = (unsigned*)alloc((size_t)BN_*1024*4);
  unsigned* mxu2  = (unsigned*)alloc((size_t)BN_*1024*4);
  size_t ztotal = off - zoff0;
  // --- end zero-once region ---
  float*    mv1  = (float*)alloc(2*64*4);
  float*    mv2  = (float*)alloc(2*128*4);
  float*    mv3  = (float*)alloc(2*1024*4);
  float*    mvL  = (float*)alloc(2*256*4);
  float*    mv6  = (float*)alloc(2*1024*4);
  float*    vbuf = (float*)alloc((size_t)BN_*1024*4);
  float*    z1   = (float*)alloc((size_t)BN_*512*4);
  float*    z2   = (float*)alloc((size_t)BN_*256*4);
  float*    T9   = (float*)alloc(72*4);
  float*    wt3q = (float*)alloc((size_t)128*1024*4);
  float*    wt2t = (float*)alloc((size_t)64*128*4);
  float*    w2p  = (float*)alloc((size_t)64*128*4);
  float*    w3p  = (float*)alloc((size_t)64*256*4);
  float*    w4p  = (float*)alloc((size_t)128*512*4);
  if (off > ws_size) return;

  float* m2t = ymt;

  const float CNTK = 8.f*1024.f*20.f;
  const float CNTN = 8.f*1024.f;

  hipMemsetAsync((char*)ws + zoff0, 0, ztotal, stream);

  // ===== weight prep =====
  k_wprep_t<<<(128*64+255)/256, 256, 0, stream>>>(tw2, wt2t, 128, 64);
  k_wprep_q<<<(1024*128)/256, 256, 0, stream>>>(tw3, wt3q, 128);
  k_wprep_mf<<<(1024*512)/256, 256, 0, stream>>>(w6, wb16);
  k_wprep_e2<<<(64*64+255)/256, 256, 0, stream>>>(w2, w2p, 64, 64);
  k_wprep_e2<<<(128*64+255)/256, 256, 0, stream>>>(w3, w3p, 128, 64);
  k_wprep_e2<<<(256*128+255)/256, 256, 0, stream>>>(w4, w4p, 256, 128);

  // ===== transform net =====
  k_transq<<<32, 256, 0, stream>>>(x, 3L*NN, 3, xt, xx);
  k_knn<<<1024, 256, 8*3*4, stream>>>(x, 3L*NN, xt, xx, idx, 3);
  k_edgeconv3<<<BN_*NN, 64, 0, stream>>>(xt, idx, tw1, ymt, sp_e1);
  k_bnfin<<<1, 64, 0, stream>>>(sp_e1, mv1, 64, CNTK);
  k_tconv2<<<BN_*NN, 64, 0, stream>>>(xt, idx, tw1, mv1, wt2t, m2t, sp_tc);
  k_bnfin<<<2, 64, 0, stream>>>(sp_tc, mv2, 128, CNTK);
  k_apply_t<<<32, 256, 0, stream>>>(m2t, mv2, 128, m2, 128L*NN, 0, nullptr, nullptr, nullptr);
  k_gemm_sm<<<BN_*64, 256, 0, stream>>>(wt3q, m2, 128L*NN, 128, mxu1, sp_g1);
  k_bnfin<<<16, 64, 0, stream>>>(sp_g1, mv3, 1024, CNTN);
  k_finmax<<<32, 256, 0, stream>>>(mxu1, mv3, vbuf);
  k_fcbn<<<128, 256, 0, stream>>>(vbuf, tfc1w, nullptr, 1024, 512, z1);
  k_fcbn<<<64, 256, 0, stream>>>(z1, tfc2w, tfc2b, 512, 256, z2);
  k_fc3w<<<18, 256, 0, stream>>>(z2, tfc3w, tfc3b, T9);
  k_tapply<<<(BN_*3*NN)/256, 256, 0, stream>>>(x, T9, xtr);

  // ===== edge conv stack =====
  k_transq<<<32, 256, 0, stream>>>(xtr, 3L*NN, 3, xt, xx);
  k_knn<<<1024, 256, 8*3*4, stream>>>(xtr, 3L*NN, xt, xx, idx, 3);
  k_edgeconv3<<<BN_*NN, 64, 0, stream>>>(xt, idx, w1, ymt, sp_L1);
  k_bnfin<<<1, 64, 0, stream>>>(sp_L1, mvL, 64, CNTK);
  k_apply_t<<<32, 256, 0, stream>>>(ymt, mvL, 64, xcat, 512L*NN, 0, xt, xx, xb16);
  // L2
  k_knn<<<1024, 256, 8*64*4, stream>>>(xcat, 512L*NN, xt, xx, idx, 64);
  k_gemm_ab<64,64><<<512, 256, 0, stream>>>(xt, w2p, ab);
  k_egather<64,16><<<512, 256, 0, stream>>>(ab, idx, ymt, sp_L2);
  k_bnfin<<<1, 64, 0, stream>>>(sp_L2, mvL, 64, CNTK);
  k_apply_t<<<32, 256, 0, stream>>>(ymt, mvL, 64, xcat, 512L*NN, 64, xt, xx, xb16);
  // L3
  k_knn<<<1024, 256, 8*64*4, stream>>>(xcat + 64L*NN, 512L*NN, xt, xx, idx, 64);
  k_gemm_ab<64,128><<<512, 256, 0, stream>>>(xt, w3p, ab);
  k_egather<128,16><<<512, 256, 0, stream>>>(ab, idx, ymt, sp_L3);
  k_bnfin<<<2, 64, 0, stream>>>(sp_L3, mvL, 128, CNTK);
  k_apply_t<<<32, 256, 0, stream>>>(ymt, mvL, 128, xcat, 512L*NN, 128, xt, xx, xb16);
  // L4
  k_knn<<<1024, 256, 8*128*4, stream>>>(xcat + 128L*NN, 512L*NN, xt, xx, idx, 128);
  k_gemm_ab<128,256><<<512, 256, 0, stream>>>(xt, w4p, ab);
  k_egather<256,16><<<512, 256, 0, stream>>>(ab, idx, ymt, sp_L4);
  k_bnfin<<<4, 64, 0, stream>>>(sp_L4, mvL, 256, CNTK);
  k_apply_t<<<32, 256, 0, stream>>>(ymt, mvL, 256, xcat, 512L*NN, 256, nullptr, nullptr, xb16);

  // ===== final conv w6 via MFMA bf16 + BN + lrelu + max over N =====
  k_gemm_mfma<<<dim3(BN_*16, 4), 256, 0, stream>>>(wb16, xb16, mxu2, sp_g2);
  k_bnfin<<<16, 64, 0, stream>>>(sp_g2, mv6, 1024, CNTN);
  k_finmax<<<32, 256, 0, stream>>>(mxu2, mv6, out);
}